// Round 6
// baseline (886.120 us; speedup 1.0000x reference)
//
#include <hip/hip_runtime.h>
#include <hip/hip_bf16.h>

#define BB 2
#define LL 4096
#define DD 1024
#define HH 4
#define DH 256
#define CH 32
#define NC (LL/CH)     // 128
#define BL (BB*LL)     // 8192
#define BLD ((size_t)BB*LL*DD) // 8388608

typedef __attribute__((ext_vector_type(8))) short short8;
typedef __attribute__((ext_vector_type(4))) float floatx4;

__device__ __forceinline__ float bf2f(unsigned short u) {
    union { float f; unsigned int i; } x; x.i = ((unsigned int)u) << 16; return x.f;
}
__device__ __forceinline__ float bflo(unsigned int u) {
    union { float f; unsigned int i; } x; x.i = u << 16; return x.f;
}
__device__ __forceinline__ float bfhi(unsigned int u) {
    union { float f; unsigned int i; } x; x.i = u & 0xFFFF0000u; return x.f;
}
__device__ __forceinline__ unsigned short f2bf(float f) {
    union { float f; unsigned int i; } x; x.f = f;
    unsigned int r = x.i + 0x7FFFu + ((x.i >> 16) & 1u);
    return (unsigned short)(r >> 16);
}
// pack two f32 -> (bf16(b)<<16)|bf16(a), round-half-up
__device__ __forceinline__ unsigned int pkbf(float a, float b) {
    unsigned int ua = __float_as_uint(a) + 0x8000u;
    unsigned int ub = __float_as_uint(b) + 0x8000u;
    return __builtin_amdgcn_perm(ub, ua, 0x07060302);
}
// barrier with LDS-only drain (no vmcnt drain -> pinned loads stay in flight)
__device__ __forceinline__ void lds_barrier() {
    __builtin_amdgcn_s_waitcnt(0xC07F);
    __builtin_amdgcn_s_barrier();
}
// asm-pinned global loads: compiler can neither sink them (volatile) nor attach its
// own conservative auto-waitcnt (it doesn't track asm loads) -- the manual counted
// s_waitcnt vmcnt(N) below is the only drain. (r1-r3: plain-C prefetch gets sunk.)
__device__ __forceinline__ short8 gload16(const void* p) {
    short8 r;
    asm volatile("global_load_dwordx4 %0, %1, off" : "=v"(r) : "v"(p) : "memory");
    return r;
}
__device__ __forceinline__ uint2 gload8(const void* p) {
    uint2 r;
    asm volatile("global_load_dwordx2 %0, %1, off" : "=v"(r) : "v"(p) : "memory");
    return r;
}

// ---------------------------------------------------------------- f32 -> bf16 bulk convert
__global__ __launch_bounds__(256) void cvt_bf_k(
    const float* __restrict__ x, unsigned short* __restrict__ y)
{
    size_t i = ((size_t)blockIdx.x * 256 + threadIdx.x) * 4;
    float4 v = *(const float4*)(x + i);
    ushort4 o;
    o.x = f2bf(v.x); o.y = f2bf(v.y); o.z = f2bf(v.z); o.w = f2bf(v.w);
    *(ushort4*)(y + i) = o;
}

// ---------------------------------------------------------------- pack w1[:,1024:1040] -> bf16 [1024][16]
__global__ __launch_bounds__(256) void w1s_prep_k(
    const float* __restrict__ w1, unsigned short* __restrict__ w1s)
{
    int idx = blockIdx.x * 256 + threadIdx.x;   // 16384
    int e = idx >> 4, s = idx & 15;
    w1s[idx] = f2bf(w1[(size_t)e * 1040 + 1024 + s]);
}

// ---------------------------------------------------------------- bf16 MFMA GEMM (NT), f32 A, f32 W
__global__ __launch_bounds__(256) void gemm_mfma(
    const float* __restrict__ A, int lda,
    const float* __restrict__ W, int ldw,
    const float* __restrict__ bias,
    float* __restrict__ C, int ldc, int K)
{
    __shared__ unsigned short Abuf[128][56];
    __shared__ unsigned short Bbuf[128][56];
    const int t = threadIdx.x;
    const int wave = t >> 6, lane = t & 63;
    const int wm = wave >> 1, wn = wave & 1;
    const int row0 = blockIdx.y * 128, col0 = blockIdx.x * 128;

    floatx4 acc[4][4];
#pragma unroll
    for (int i = 0; i < 4; ++i)
#pragma unroll
        for (int j = 0; j < 4; ++j) acc[i][j] = (floatx4){0.f, 0.f, 0.f, 0.f};

    const int fr = lane & 15, fk = (lane >> 4) * 8;

    for (int kt = 0; kt < K; kt += 32) {
        __syncthreads();
#pragma unroll
        for (int it = 0; it < 2; ++it) {
            int idx = t + it * 256;
            int r = idx >> 2, s = (idx & 3) * 8;
            const float* ap = A + (size_t)(row0 + r) * lda + kt + s;
            float4 a0 = *(const float4*)(ap);
            float4 a1 = *(const float4*)(ap + 4);
            ushort4 p0, p1;
            p0.x = f2bf(a0.x); p0.y = f2bf(a0.y); p0.z = f2bf(a0.z); p0.w = f2bf(a0.w);
            p1.x = f2bf(a1.x); p1.y = f2bf(a1.y); p1.z = f2bf(a1.z); p1.w = f2bf(a1.w);
            *(ushort4*)&Abuf[r][s]     = p0;
            *(ushort4*)&Abuf[r][s + 4] = p1;
            const float* wp = W + (size_t)(col0 + r) * ldw + kt + s;
            float4 b0 = *(const float4*)(wp);
            float4 b1 = *(const float4*)(wp + 4);
            ushort4 q0, q1;
            q0.x = f2bf(b0.x); q0.y = f2bf(b0.y); q0.z = f2bf(b0.z); q0.w = f2bf(b0.w);
            q1.x = f2bf(b1.x); q1.y = f2bf(b1.y); q1.z = f2bf(b1.z); q1.w = f2bf(b1.w);
            *(ushort4*)&Bbuf[r][s]     = q0;
            *(ushort4*)&Bbuf[r][s + 4] = q1;
        }
        __syncthreads();

        short8 afrag[4], bfrag[4];
#pragma unroll
        for (int i = 0; i < 4; ++i) {
            afrag[i] = *(const short8*)&Abuf[wm * 64 + i * 16 + fr][fk];
            bfrag[i] = *(const short8*)&Bbuf[wn * 64 + i * 16 + fr][fk];
        }
#pragma unroll
        for (int i = 0; i < 4; ++i)
#pragma unroll
            for (int j = 0; j < 4; ++j)
                acc[i][j] = __builtin_amdgcn_mfma_f32_16x16x32_bf16(
                    afrag[i], bfrag[j], acc[i][j], 0, 0, 0);
    }

    const int fc = lane & 15, frow = (lane >> 4) * 4;
#pragma unroll
    for (int j = 0; j < 4; ++j) {
        int col = col0 + wn * 64 + j * 16 + fc;
        float bv = bias ? bias[col] : 0.0f;
#pragma unroll
        for (int i = 0; i < 4; ++i) {
#pragma unroll
            for (int r = 0; r < 4; ++r) {
                int row = row0 + wm * 64 + i * 16 + frow + r;
                C[(size_t)row * ldc + col] = acc[i][j][r] + bv;
            }
        }
    }
}

// ---------------------------------------------------------------- bf16 MFMA GEMM (NT), bf16 A, bf16 B
__global__ __launch_bounds__(256) void gemm_bb(
    const unsigned short* __restrict__ A, int lda,
    const unsigned short* __restrict__ B, int ldb,
    float* __restrict__ C, int ldc, int K)
{
    __shared__ unsigned short Abuf[128][56];
    __shared__ unsigned short Bbuf[128][56];
    const int t = threadIdx.x;
    const int wave = t >> 6, lane = t & 63;
    const int wm = wave >> 1, wn = wave & 1;
    const int row0 = blockIdx.y * 128, col0 = blockIdx.x * 128;

    floatx4 acc[4][4];
#pragma unroll
    for (int i = 0; i < 4; ++i)
#pragma unroll
        for (int j = 0; j < 4; ++j) acc[i][j] = (floatx4){0.f, 0.f, 0.f, 0.f};

    const int fr = lane & 15, fk = (lane >> 4) * 8;

    for (int kt = 0; kt < K; kt += 32) {
        __syncthreads();
#pragma unroll
        for (int it = 0; it < 2; ++it) {
            int idx = t + it * 256;
            int r = idx >> 2, s = (idx & 3) * 8;
            uint4 av = *(const uint4*)(A + (size_t)(row0 + r) * lda + kt + s);
            *(uint4*)&Abuf[r][s] = av;
            uint4 bv = *(const uint4*)(B + (size_t)(col0 + r) * ldb + kt + s);
            *(uint4*)&Bbuf[r][s] = bv;
        }
        __syncthreads();

        short8 afrag[4], bfrag[4];
#pragma unroll
        for (int i = 0; i < 4; ++i) {
            afrag[i] = *(const short8*)&Abuf[wm * 64 + i * 16 + fr][fk];
            bfrag[i] = *(const short8*)&Bbuf[wn * 64 + i * 16 + fr][fk];
        }
#pragma unroll
        for (int i = 0; i < 4; ++i)
#pragma unroll
            for (int j = 0; j < 4; ++j)
                acc[i][j] = __builtin_amdgcn_mfma_f32_16x16x32_bf16(
                    afrag[i], bfrag[j], acc[i][j], 0, 0, 0);
    }

    const int fc = lane & 15, frow = (lane >> 4) * 4;
#pragma unroll
    for (int j = 0; j < 4; ++j) {
        int col = col0 + wn * 64 + j * 16 + fc;
#pragma unroll
        for (int i = 0; i < 4; ++i) {
#pragma unroll
            for (int r = 0; r < 4; ++r) {
                int row = row0 + wm * 64 + i * 16 + frow + r;
                C[(size_t)row * ldc + col] = acc[i][j][r];
            }
        }
    }
}

// --------------------------------------- causal dwconv K=4 + silu + head-l2norm -> bf16
__global__ __launch_bounds__(256) void convnorm_qk_k(
    const float* __restrict__ x, const float* __restrict__ w,
    unsigned short* __restrict__ y)
{
    int bl = blockIdx.x >> 2;
    int h  = blockIdx.x & 3;
    int l  = bl & (LL - 1);
    int d  = threadIdx.x;
    int c  = h * DH + d;
    const float* wp = w + (size_t)c * 4;
    const float* xp = x + (size_t)bl * DD + c;
    float acc = wp[3] * xp[0];
    if (l >= 1) acc += wp[2] * xp[-(int)DD];
    if (l >= 2) acc += wp[1] * xp[-2*(int)DD];
    if (l >= 3) acc += wp[0] * xp[-3*(int)DD];
    acc = acc / (1.0f + expf(-acc));
    float s = acc * acc;
#pragma unroll
    for (int off = 32; off > 0; off >>= 1) s += __shfl_down(s, off);
    __shared__ float red[4];
    int wv = threadIdx.x >> 6, ln = threadIdx.x & 63;
    if (ln == 0) red[wv] = s;
    __syncthreads();
    float tot = red[0] + red[1] + red[2] + red[3];
    y[(size_t)bl * DD + c] = f2bf(acc * rsqrtf(tot));
}

// ------------------------------------------------- causal depthwise conv K=4 + silu (f32)
__global__ __launch_bounds__(256) void conv_silu_k(
    const float* __restrict__ x, const float* __restrict__ w, float* __restrict__ y)
{
    size_t idx = (size_t)blockIdx.x * 256 + threadIdx.x;
    int c = (int)(idx & (DD - 1));
    int bl = (int)(idx >> 10);
    int l = bl & (LL - 1);
    const float* wp = w + (size_t)c * 4;
    const float* xp = x + (size_t)bl * DD + c;
    float acc = wp[3] * xp[0];
    if (l >= 1) acc += wp[2] * xp[-(int)DD];
    if (l >= 2) acc += wp[1] * xp[-2*(int)DD];
    if (l >= 3) acc += wp[0] * xp[-3*(int)DD];
    y[idx] = acc / (1.0f + expf(-acc));
}

// ------------------------------------------------- FIR causal depthwise conv, LDS-tiled
template<int K>
__global__ __launch_bounds__(256) void fir2_k(
    const float* __restrict__ x, const float* __restrict__ filt, float* __restrict__ y)
{
    const int ctile = blockIdx.x & 15;
    const int ltile = (blockIdx.x >> 4) & 63;
    const int b = blockIdx.x >> 10;
    const int RT = 64 + K - 1;
    __shared__ float xs[RT][64];
    __shared__ float fs[64][K + 1];
    const int t = threadIdx.x;
    const int l0 = ltile * 64;

    for (int i = t; i < RT * 16; i += 256) {
        int li = i >> 4, c4 = (i & 15) * 4;
        int l = l0 - (K - 1) + li;
        float4 v = make_float4(0.f, 0.f, 0.f, 0.f);
        if (l >= 0)
            v = *(const float4*)(x + ((size_t)b * LL + l) * DD + ctile * 64 + c4);
        *(float4*)&xs[li][c4] = v;
    }
    for (int i = t; i < 64 * K; i += 256) {
        fs[i / K][i % K] = filt[(size_t)ctile * 64 * K + i];
    }
    __syncthreads();

    const int c = t & 63, lg = t >> 6;
    float acc[16];
#pragma unroll
    for (int o = 0; o < 16; ++o) acc[o] = 0.f;
#pragma unroll
    for (int j = 0; j < 16 + K - 1; ++j) {
        float xv = xs[lg * 16 + j][c];
#pragma unroll
        for (int o = 0; o < 16; ++o) {
            int tap = j - o;
            if (tap >= 0 && tap < K) acc[o] += fs[c][tap] * xv;
        }
    }
    size_t base = ((size_t)b * LL + l0 + lg * 16) * DD + ctile * 64 + c;
#pragma unroll
    for (int o = 0; o < 16; ++o)
        y[base + (size_t)o * DD] = acc[o];
}

// ------------------------------------------------- beta = sigmoid(hs @ b_proj^T)
__global__ __launch_bounds__(256) void beta_k(
    const float* __restrict__ hs, const float* __restrict__ bw, float* __restrict__ beta)
{
    int bl = blockIdx.x;
    const float* xr = hs + (size_t)bl * DD;
    float a0=0.f,a1=0.f,a2=0.f,a3=0.f;
    for (int k = threadIdx.x; k < DD; k += 256) {
        float xv = xr[k];
        a0 += xv * bw[k];
        a1 += xv * bw[DD + k];
        a2 += xv * bw[2*DD + k];
        a3 += xv * bw[3*DD + k];
    }
#pragma unroll
    for (int off = 32; off > 0; off >>= 1) {
        a0 += __shfl_down(a0, off); a1 += __shfl_down(a1, off);
        a2 += __shfl_down(a2, off); a3 += __shfl_down(a3, off);
    }
    __shared__ float red[4][4];
    int wv = threadIdx.x >> 6, ln = threadIdx.x & 63;
    if (ln == 0) { red[wv][0]=a0; red[wv][1]=a1; red[wv][2]=a2; red[wv][3]=a3; }
    __syncthreads();
    if (threadIdx.x < 4) {
        int h = threadIdx.x;
        float s = red[0][h] + red[1][h] + red[2][h] + red[3][h];
        beta[(size_t)bl * HH + h] = 1.0f / (1.0f + expf(-s));
    }
}

// ------------------------------------------------- k transpose: k[b,l,h*DH+e] -> kT[bh,e,l]
__global__ __launch_bounds__(256) void tr_k(
    const unsigned short* __restrict__ k, unsigned short* __restrict__ kT)
{
    int et = blockIdx.x & 3;
    int lt = (blockIdx.x >> 2) & 63;
    int bh = blockIdx.x >> 8;
    int h = bh & 3, b = bh >> 2;
    __shared__ unsigned short tile[64][72];
    int t = threadIdx.x;
    int tr = t >> 4;
    int tc = (t & 15) * 4;
#pragma unroll
    for (int i = 0; i < 4; ++i) {
        int l = tr + i * 16;
        ushort4 v = *(const ushort4*)(k + ((size_t)b * LL + lt*64 + l) * DD + h * DH + et*64 + tc);
        *(ushort4*)&tile[l][tc] = v;
    }
    __syncthreads();
#pragma unroll
    for (int i = 0; i < 4; ++i) {
        int e = tr + i * 16;
        ushort4 v;
        v.x = tile[tc+0][e]; v.y = tile[tc+1][e];
        v.z = tile[tc+2][e]; v.w = tile[tc+3][e];
        *(ushort4*)(kT + ((size_t)bh * DH + et*64 + e) * LL + (size_t)lt*64 + tc) = v;
    }
}

// ------------------------------------------------- chunk prep v2: MFMA everywhere.
__global__ __launch_bounds__(256) void chunk_prep2_k(
    const unsigned short* __restrict__ q, const unsigned short* __restrict__ k,
    const unsigned short* __restrict__ kT, const float* __restrict__ v,
    const float* __restrict__ beta,
    unsigned short* __restrict__ uT, unsigned short* __restrict__ w_out,
    unsigned short* __restrict__ attn_out)
{
    const int ci = blockIdx.x & (NC - 1);
    const int bh = blockIdx.x >> 7;
    const int h = bh & (HH - 1), b = bh >> 2;
    __shared__ unsigned short kL[32][264];
    __shared__ unsigned short qL[32][264];
    __shared__ float vL[32][260];
    __shared__ float AmL[32][33];
    __shared__ unsigned short AbH[32][40];
    __shared__ unsigned short AbL2[32][40];
    __shared__ float betL[32];
    const int t = threadIdx.x;
    const int wave = t >> 6, lane = t & 63;
    const int lr = lane & 15, lg = lane >> 4;
    const int l0 = ci * CH;
    const size_t rowbase = (size_t)b * LL + l0;

    // ---- phase 1: stage k,q (bf16, padded rows) + v (f32, padded) + beta
    for (int i = t; i < 1024; i += 256) {
        int r = i >> 5, s8 = (i & 31) * 8;
        *(uint4*)&kL[r][s8] = *(const uint4*)(k + (rowbase + r) * DD + h * DH + s8);
        *(uint4*)&qL[r][s8] = *(const uint4*)(q + (rowbase + r) * DD + h * DH + s8);
    }
    for (int i = t; i < 2048; i += 256) {
        int e = i >> 6, d4 = (i & 63) * 4;
        *(float4*)&vL[e][d4] = *(const float4*)(v + (rowbase + e) * DD + h * DH + d4);
    }
    if (t < 32) betL[t] = beta[(rowbase + t) * HH + h];
    __syncthreads();

    // ---- phase 2: per-wave 16x16 tile of Am (k k^T) and attn (q k^T), K=256
    const int mt = wave >> 1, nt = wave & 1;
    floatx4 accA = (floatx4){0.f,0.f,0.f,0.f}, accT = accA;
#pragma unroll
    for (int ks = 0; ks < 8; ++ks) {
        short8 bk = *(const short8*)&kL[nt * 16 + lr][ks * 32 + lg * 8];
        short8 ak = *(const short8*)&kL[mt * 16 + lr][ks * 32 + lg * 8];
        short8 aq = *(const short8*)&qL[mt * 16 + lr][ks * 32 + lg * 8];
        accA = __builtin_amdgcn_mfma_f32_16x16x32_bf16(ak, bk, accA, 0, 0, 0);
        accT = __builtin_amdgcn_mfma_f32_16x16x32_bf16(aq, bk, accT, 0, 0, 0);
    }
    {
        const size_t abase = (size_t)blockIdx.x * (CH * CH);
        const int ee = nt * 16 + lr;
#pragma unroll
        for (int r = 0; r < 4; ++r) {
            int c = mt * 16 + lg * 4 + r;
            float bc = betL[c];
            AmL[c][ee] = (ee < c) ? (-bc * accA[r]) : 0.0f;
            attn_out[abase + (size_t)c * CH + ee] =
                (ee <= c) ? f2bf(accT[r]) : (unsigned short)0;
        }
    }
    __syncthreads();

    // pre-issue w's B-frags from global kT (latency hides under substitution)
    const unsigned short* kTg = kT + (size_t)bh * DH * LL;
    short8 wB[4];
#pragma unroll
    for (int n = 0; n < 4; ++n)
        wB[n] = *(const short8*)(kTg + (size_t)(wave * 64 + n * 16 + lr) * LL + l0 + lg * 8);

    // ---- phase 3: wave 0 forward-substitution, column-per-lane in registers
    if (wave == 0) {
        const int j = lane & 31;
        float col[32];
#pragma unroll
        for (int c = 0; c < 32; ++c) col[c] = AmL[c][j];
#pragma unroll
        for (int i = 1; i < 32; ++i) {
            float u0 = 0.f, u1 = 0.f;
#pragma unroll
            for (int kk = 0; kk < 32; kk += 2) {
                if (kk < i)     u0 += __shfl(col[i], kk) * col[kk];
                if (kk + 1 < i) u1 += __shfl(col[i], kk + 1) * col[kk + 1];
            }
            if (j < i) col[i] += u0 + u1;
        }
        if (lane < 32) {
            const float bj = betL[j];
#pragma unroll
            for (int c = 0; c < 32; ++c) {
                float val = (col[c] + (c == j ? 1.0f : 0.0f)) * bj;
                unsigned short hi = f2bf(val);
                AbH[c][j] = hi;
                AbL2[c][j] = f2bf(val - bf2f(hi));
            }
        }
    }
    __syncthreads();

    // ---- phase 4: u^T = (Ab @ v)^T direct to uT; w = Ab @ k. Dual-bf16 Ab.
    short8 AH[2], ALo[2];
#pragma unroll
    for (int m = 0; m < 2; ++m) {
        AH[m]  = *(const short8*)&AbH[m * 16 + lr][lg * 8];
        ALo[m] = *(const short8*)&AbL2[m * 16 + lr][lg * 8];
    }
    const size_t uTbase = (size_t)bh * DH * LL;
    const size_t wbase  = (size_t)bh * LL * DH;
#pragma unroll
    for (int n = 0; n < 4; ++n) {
        const int d = wave * 64 + n * 16 + lr;
        union { short8 s8; unsigned int u[4]; } vf;
#pragma unroll
        for (int p2 = 0; p2 < 4; ++p2)
            vf.u[p2] = pkbf(vL[lg * 8 + p2 * 2][d], vL[lg * 8 + p2 * 2 + 1][d]);
#pragma unroll
        for (int m = 0; m < 2; ++m) {
            floatx4 au = (floatx4){0.f,0.f,0.f,0.f};
            au = __builtin_amdgcn_mfma_f32_16x16x32_bf16(AH[m],  vf.s8, au, 0, 0, 0);
            au = __builtin_amdgcn_mfma_f32_16x16x32_bf16(ALo[m], vf.s8, au, 0, 0, 0);
            ushort4 ou;
            ou.x = f2bf(au[0]); ou.y = f2bf(au[1]); ou.z = f2bf(au[2]); ou.w = f2bf(au[3]);
            *(ushort4*)(uT + uTbase + (size_t)d * LL + l0 + m * 16 + lg * 4) = ou;

            floatx4 aw = (floatx4){0.f,0.f,0.f,0.f};
            aw = __builtin_amdgcn_mfma_f32_16x16x32_bf16(AH[m],  wB[n], aw, 0, 0, 0);
            aw = __builtin_amdgcn_mfma_f32_16x16x32_bf16(ALo[m], wB[n], aw, 0, 0, 0);
#pragma unroll
            for (int r = 0; r < 4; ++r)
                w_out[wbase + (size_t)(l0 + m * 16 + lg * 4 + r) * DH + d] = f2bf(aw[r]);
        }
    }
}

// ------------------------------------------------- chunk scan v12: scan6 wave roles with
// asm-PINNED register prefetch + counted vmcnt. All per-wave-private operands (w/q rows,
// kT rows, attn, uT: 13 loads/wave/chunk) are loaded one chunk ahead via asm volatile
// global_load (compiler can't sink them, and inserts no auto-waitcnt for them); a single
// manual counted s_waitcnt vmcnt(13|17) + sched_barrier(0) drains exactly chunk ci's
// loads while ci+1's stay in flight. Only cross-wave-shared data (SbT, uadjT) touches
// LDS, single-buffered (barrier-separated): LDS traffic 146KB -> 45KB/chunk vs scan10.
// w23 allow 4 extra outstanding (their O-stores); vmcnt in-order accounting audited.
__global__ __launch_bounds__(256, 1) void scan12_k(
    const unsigned short* __restrict__ q, const unsigned short* __restrict__ kT,
    const unsigned short* __restrict__ uT, const unsigned short* __restrict__ w,
    const unsigned short* __restrict__ attn, float* __restrict__ dout)
{
    const int bh = blockIdx.x & 7;     // low bits -> 16 same-bh blocks share one XCD
    const int jb = blockIdx.x >> 3;
    const int h = bh & (HH - 1), b = bh >> 2;
    const int jcol = jb * 16;
    const int wave = threadIdx.x >> 6, lane = threadIdx.x & 63;
    const int lr = lane & 15, lg = lane >> 4;
    const int half = wave & 1;
    const bool isQ = wave >= 2;

    __shared__ unsigned short SbT[16][264];    // [col][e] bf16 (single buffer)
    __shared__ unsigned short uadjT[16][40];   // [col][cc] bf16 (single buffer)

    floatx4 Sacc[4];
#pragma unroll
    for (int mt = 0; mt < 4; ++mt) Sacc[mt] = (floatx4){0.f,0.f,0.f,0.f};

    const unsigned short* qb  = q + (size_t)b * LL * DD + h * DH;
    const unsigned short* wb  = w + (size_t)bh * LL * DH;
    const unsigned short* ob  = isQ ? qb : wb;
    const size_t ost          = isQ ? (size_t)DD : (size_t)DH;
    const unsigned short* orow0 = ob + (size_t)(half * 16 + lr) * ost + lg * 8;
    const unsigned short* kTb = kT + (size_t)bh * DH * LL
                                + (size_t)(64 * wave + lr) * LL + lg * 8;
    const unsigned short* uTb = uT + ((size_t)bh * DH + jcol + lr) * LL + half * 16 + lg * 4;
    const unsigned short* atb = attn + (size_t)bh * NC * (CH * CH)
                                + (size_t)(half * 16 + lr) * CH + lg * 8;
    float* db = dout + (size_t)bh * LL * DH;

    short8 po[2][8];     // this wave's A rows (w or q), K=256
    short8 pk[2][4];     // kT A-frags for S-update
    short8 pa[2];        // attn frag (waves 2,3)
    uint2  pu[2];        // u elems (waves 0,1)

    // 13 pinned loads for chunk cn into register slot s (uniform count all waves)
#define ISSUE13(cn, s)                                                          \
    {                                                                           \
        const int ln_ = (cn) * CH;                                              \
        const unsigned short* orow_ = orow0 + (size_t)ln_ * ost;                \
        po[s][0] = gload16(orow_ + 0*32);  po[s][1] = gload16(orow_ + 1*32);    \
        po[s][2] = gload16(orow_ + 2*32);  po[s][3] = gload16(orow_ + 3*32);    \
        po[s][4] = gload16(orow_ + 4*32);  po[s][5] = gload16(orow_ + 5*32);    \
        po[s][6] = gload16(orow_ + 6*32);  po[s][7] = gload16(orow_ + 7*32);    \
        pk[s][0] = gload16(kTb + (size_t)(0*16) * LL + ln_);                    \
        pk[s][1] = gload16(kTb + (size_t)(1*16) * LL + ln_);                    \
        pk[s][2] = gload16(kTb + (size_t)(2*16) * LL + ln_);                    \
        pk[s][3] = gload16(kTb + (size_t)(3*16) * LL + ln_);                    \
        if (!isQ) pu[s] = gload8(uTb + ln_);                                    \
        else      pa[s] = gload16(atb + (size_t)(cn) * (CH * CH));              \
    }

    // prologue: pin chunk 0's loads -> slot 0
    ISSUE13(0, 0);

#pragma unroll 2
    for (int ci = 0; ci < NC; ++ci) {
        const int p = ci & 1;
        const int l0 = ci * CH;

        // 1) issue pinned loads for chunk ci+1 (clamped tail keeps counts uniform)
        {
            const int cn = (ci + 1 < NC) ? (ci + 1) : ci;
            ISSUE13(cn, p ^ 1);
        }

        // 2) pack wave's S e-slice -> SbT (readers of prev chunk done before bar (b))
#pragma unroll
        for (int mt = 0; mt < 4; ++mt) {
            int e0 = 64 * wave + 16 * mt + lg * 4;
            *(uint2*)&SbT[lr][e0] = make_uint2(pkbf(Sacc[mt][0], Sacc[mt][1]),
                                               pkbf(Sacc[mt][2], Sacc[mt][3]));
        }
        lds_barrier();   // (a) SbT published; uadjT reads of ci-1 closed

        // 3) counted drain: exactly chunk ci's 13 loads, ci+1's stay in flight.
        //    w01 newer ops: loads(ci+1)=13. w23 newer: stores(ci-1)=4 + loads(ci+1)=13
        //    (ci==0: no stores yet -> 13).
        if (!isQ || ci == 0) { asm volatile("s_waitcnt vmcnt(13)" ::: "memory"); }
        else                 { asm volatile("s_waitcnt vmcnt(17)" ::: "memory"); }
        __builtin_amdgcn_sched_barrier(0);   // nothing (esp. MFMA/VALU) hoists above

        // 4) P = A @ S over full K=256 (two independent chains for ILP)
        floatx4 Pa = (floatx4){0.f,0.f,0.f,0.f}, Pb = Pa;
#pragma unroll
        for (int kt = 0; kt < 4; ++kt) {
            short8 s0 = *(const short8*)&SbT[lr][(2*kt)   * 32 + lg * 8];
            short8 s1 = *(const short8*)&SbT[lr][(2*kt+1) * 32 + lg * 8];
            Pa = __builtin_amdgcn_mfma_f32_16x16x32_bf16(po[p][2*kt],   s0, Pa, 0,0,0);
            Pb = __builtin_amdgcn_mfma_f32_16x16x32_bf16(po[p][2*kt+1], s1, Pb, 0,0,0);
        }
        floatx4 P = Pa + Pb;

        // 5) waves 0,1: uadj = u - w@S -> uadjT
        if (!isQ) {
            float ua0 = bflo(pu[p].x) - P[0];
            float ua1 = bfhi(pu[p].x) - P[1];
            float ua2 = bflo(pu[p].y) - P[2];
            float ua3 = bfhi(pu[p].y) - P[3];
            int cc0 = half * 16 + lg * 4;
            *(uint2*)&uadjT[lr][cc0] = make_uint2(pkbf(ua0, ua1), pkbf(ua2, ua3));
        }
        lds_barrier();   // (b) uadjT visible; SbT reads of this chunk closed

        short8 ub = *(const short8*)&uadjT[lr][lg * 8];

        // 6) waves 2,3: O = q@S + attn@uadj -> dout (4 stores/chunk, counted above)
        if (isQ) {
            floatx4 Ot = __builtin_amdgcn_mfma_f32_16x16x32_bf16(pa[p], ub, P, 0,0,0);
#pragma unroll
            for (int r = 0; r < 4; ++r)
                db[(size_t)(l0 + half * 16 + lg * 4 + r) * DH + jcol + lr] = Ot[r];
        }

        // 7) S e-slice += kT @ uadj
#pragma unroll
        for (int mt = 0; mt < 4; ++mt)
            Sacc[mt] = __builtin_amdgcn_mfma_f32_16x16x32_bf16(pk[p][mt], ub, Sacc[mt], 0,0,0);
    }
#undef ISSUE13
}

// ------------------------------------------------- per-head stats
__global__ __launch_bounds__(256) void stats_k(
    const float* __restrict__ ls, const float* __restrict__ llb,
    const float* __restrict__ dox, const float* __restrict__ v,
    float* __restrict__ stats)
{
    int bl = blockIdx.x;
    int b = bl >> 12, l = bl & (LL - 1);
    int wv = threadIdx.x >> 6, ln = threadIdx.x & 63;
    size_t ibase = (size_t)bl * DD + wv * DH;
    size_t dbase = (((size_t)(b * HH + wv)) * LL + l) * DH;
#pragma unroll
    for (int tn = 0; tn < 4; ++tn) {
        const float* p; size_t base;
        if (tn == 0)      { p = ls;  base = ibase; }
        else if (tn == 1) { p = llb; base = ibase; }
        else if (tn == 2) { p = dox; base = dbase; }
        else              { p = v;   base = ibase; }
        float4 x = *(const float4*)(p + base + ln * 4);
        float sm = x.x + x.y + x.z + x.w;
        float sq = x.x*x.x + x.y*x.y + x.z*x.z + x.w*x.w;
        float sa = fabsf(x.x) + fabsf(x.y) + fabsf(x.z) + fabsf(x.w);
#pragma unroll
        for (int off = 32; off > 0; off >>= 1) {
            sm += __shfl_down(sm, off);
            sq += __shfl_down(sq, off);
            sa += __shfl_down(sa, off);
        }
        if (ln == 0) {
            float mean = sm * (1.0f / DH);
            float var = sq * (1.0f / DH) - mean * mean;
            float am = sa * (1.0f / DH);
            float l2 = sqrtf(sq);
            *(float4*)(stats + (size_t)bl * 64 + wv * 16 + tn * 4) =
                make_float4(mean, var, am, l2);
        }
    }
}

// ------------------------------------------------- gate finish v2
__global__ __launch_bounds__(256) void gate_fin2_k(
    const float* __restrict__ hpart, const float* __restrict__ stats,
    const unsigned short* __restrict__ w1s,
    const float* __restrict__ w2, const float* __restrict__ b2,
    const float* __restrict__ ltemp, float* __restrict__ fw)
{
    const int bl = blockIdx.x;
    const int t = threadIdx.x;
    const float temp = log1pf(expf(ltemp[0])) + 1e-4f;
    __shared__ float st[HH][16];
    __shared__ float red[4][16];
    __shared__ float fin[16];
    if (t < 64) st[t >> 4][t & 15] = stats[(size_t)bl * 64 + t];

    const int e0 = t * 4;
    float4 hp4 = *(const float4*)(hpart + (size_t)bl * DD + e0);
    float hp[4] = {hp4.x, hp4.y, hp4.z, hp4.w};
    float w2a[4][4];
#pragma unroll
    for (int j = 0; j < 4; ++j) {
        float4 wv = *(const float4*)(w2 + (size_t)j * 1024 + e0);
        w2a[j][0] = wv.x; w2a[j][1] = wv.y; w2a[j][2] = wv.z; w2a[j][3] = wv.w;
    }
    uint4 wpk[8];
    const uint4* wp = (const uint4*)(w1s + (size_t)e0 * 16);
#pragma unroll
    for (int i = 0; i < 8; ++i) wpk[i] = wp[i];
    __syncthreads();

    float lg[4][4];
#pragma unroll
    for (int h = 0; h < 4; ++h)
#pragma unroll
        for (int j = 0; j < 4; ++j) lg[h][j] = 0.0f;

#pragma unroll
    for (int ii = 0; ii < 4; ++ii) {
        float xh[4] = {hp[ii], hp[ii], hp[ii], hp[ii]};
        unsigned arr[8] = {wpk[ii*2].x, wpk[ii*2].y, wpk[ii*2].z, wpk[ii*2].w,
                           wpk[ii*2+1].x, wpk[ii*2+1].y, wpk[ii*2+1].z, wpk[ii*2+1].w};
#pragma unroll
        for (int p = 0; p < 8; ++p) {
            float wlo = bflo(arr[p]), whi = bfhi(arr[p]);
            int s = p * 2;
#pragma unroll
            for (int h = 0; h < 4; ++h)
                xh[h] += st[h][s] * wlo + st[h][s + 1] * whi;
        }
#pragma unroll
        for (int h = 0; h < 4; ++h) {
            float x = xh[h];
            float gct = 0.5f * x * (1.0f + erff(x * 0.70710678118654752f));
            lg[h][0] += gct * w2a[0][ii];
            lg[h][1] += gct * w2a[1][ii];
            lg[h][2] += gct * w2a[2][ii];
            lg[h][3] += gct * w2a[3][ii];
        }
    }

#pragma unroll
    for (int h = 0; h < 4; ++h)
#pragma unroll
        for (int j = 0; j < 4; ++j)
#pragma unroll
            for (int off = 32; off > 0; off >>= 1)
                lg[h][j] += __shfl_down(lg[h][j], off);

    const int wv = t >> 6, ln = t & 63;
    if (ln == 0) {
#pragma unroll
        for (int h = 0; h < 4; ++h)
#pragma unroll
            for (int j = 0; j < 4; ++j) red[wv][h * 4 + j] = lg[h][j];
    }
    __syncthreads();
    if (t < 16) {
        float s = red[0][t] + red[1][t] + red[2][t] + red[3][t] + b2[t & 3];
        fin[t] = s / temp;
    }
    __syncthreads();
    if (t < 4) {
        float l0 = fin[t*4], l1 = fin[t*4+1], l2 = fin[t*4+2], l3 = fin[t*4+3];
        float m = fmaxf(fmaxf(l0, l1), fmaxf(l2, l3));
        float e0x = expf(l0-m), e1 = expf(l1-m), e2 = expf(l2-m), e3 = expf(l3-m);
        float inv = 1.0f / (e0x + e1 + e2 + e3);
        *(float4*)(fw + (size_t)bl * 16 + t * 4) = make_float4(e0x*inv, e1*inv, e2*inv, e3*inv);
    }
}

// ------------------------------------------------- combine + rms norm
__global__ __launch_bounds__(256) void combine_k(
    const float* __restrict__ ls, const float* __restrict__ llb,
    const float* __restrict__ dox, const float* __restrict__ v,
    const float* __restrict__ fw, const float* __restrict__ rss,
    const float* __restrict__ rsl, const float* __restrict__ onw,
    float* __restrict__ opre)
{
    int h = blockIdx.x & (HH - 1);
    int bl = blockIdx.x >> 2;
    int b = bl >> 12, l = bl & (LL - 1);
    int d = threadIdx.x;
    size_t i1 = (size_t)blockIdx.x * DH + d;
    size_t i2 = (((size_t)(b * HH + h)) * LL + l) * DH + d;
    const float* fwp = fw + (size_t)blockIdx.x * 4;
    float f0 = fwp[0], f1 = fwp[1], f2 = fwp[2], f3 = fwp[3];
    float aS = rss[0], aL = rsl[0];
    float vls = ls[i1], vll = llb[i1], vd = dox[i2], vv = v[i1];
    float o = f0*vls + f1*vll + f2*vd + f3*vv + aS*vls + aL*vll;
    float s = o * o;
#pragma unroll
    for (int off = 32; off > 0; off >>= 1) s += __shfl_down(s, off);
    __shared__ float red[4];
    int wv = threadIdx.x >> 6, ln = threadIdx.x & 63;
    if (ln == 0) red[wv] = s;
    __syncthreads();
    float ms = (red[0] + red[1] + red[2] + red[3]) * (1.0f / DH);
    opre[(size_t)bl * DD + h * DH + d] = o * rsqrtf(ms + 1e-5f) * onw[d];
}

// ================================================================ launch
extern "C" void kernel_launch(void* const* d_in, const int* in_sizes, int n_in,
                              void* d_out, int out_size, void* d_ws, size_t ws_size,
                              hipStream_t stream)
{
    const float* hs  = (const float*)d_in[0];
    const float* qw  = (const float*)d_in[1];
    const float* kw  = (const float*)d_in[2];
    const float* vw  = (const float*)d_in[3];
    const float* bw  = (const float*)d_in[4];
    const float* qcw = (const float*)d_in[5];
    const float* kcw = (const float*)d_in[6];
    const float* vcw = (const float*)d_in[7];
    const float* fsw = (const float*)d_in[8];
    const float* flw = (const float*)d_in[9];
    const float* w1  = (const float*)d_in[10];
    const float* b1  = (const float*)d_in[11];
    const float* w2  = (const float*)d_in[12];
    const float* b2  = (const float*)d_in[13];
    const float* lt  = (const float*)d_in[14];
    const float* rss = (const float*)d_in[15];
    const float* rsl = (const float*)d_in[16];
    const float* onw = (const float*)d_in[17];
    const float* opw = (const float*)d_in[18];
    float* out = (float*)d_out;

    float* wsf = (float*)d_ws;
    float* tmp   = wsf;
    unsigned short* ktbuf = (unsigned short*)tmp;
    unsigned short* uTbuf = (unsigned short*)(wsf + BLD/2);
    float* vbuf  = wsf + BLD;
    float* dbuf  = wsf + 2*BLD;
    // hsb shares the dbuf region -> DEAD once scan12 writes dbuf. Only used in phase 1.
    unsigned short* hsb = (unsigned short*)(wsf + 2*BLD);
    // bf16 QKV weights live in the dead second half of the dbuf region during phase 1
    unsigned short* qwb = (unsigned short*)(wsf + 2*BLD + BLD/2);
    unsigned short* kwb = qwb + (size_t)DD*DD;
    unsigned short* vwb = kwb + (size_t)DD*DD;
    unsigned short* qbuf = (unsigned short*)(wsf + 3*BLD);
    unsigned short* kbuf = qbuf + BLD;
    float* hpart = wsf + 3*BLD;
    float* opre  = wsf + 3*BLD;
    unsigned short* ubuf = (unsigned short*)(wsf + 4*BLD);
    unsigned short* wbuf = ubuf + BLD;
    float* llbuf = wsf + 4*BLD;
    float* lsbuf = tmp;
    unsigned short* attnb = (unsigned short*)(wsf + 5*BLD);
    float* statsb = wsf + 5*BLD + 524288;
    float* fwbuf  = statsb + (size_t)BL*HH*16;
    float* betab  = fwbuf + (size_t)BL*HH*4;
    unsigned short* w1sp = (unsigned short*)(betab + (size_t)BL*HH);

    dim3 gg(8, 64);   // N/128, M/128

    cvt_bf_k<<<(int)(BLD/1024), 256, 0, stream>>>(hs, hsb);
    cvt_bf_k<<<1024, 256, 0, stream>>>(qw, qwb);
    cvt_bf_k<<<1024, 256, 0, stream>>>(kw, kwb);
    cvt_bf_k<<<1024, 256, 0, stream>>>(vw, vwb);
    w1s_prep_k<<<64, 256, 0, stream>>>(w1, w1sp);

    gemm_bb<<<gg, 256, 0, stream>>>(hsb, DD, qwb, DD, tmp, DD, DD);
    convnorm_qk_k<<<BL*HH, 256, 0, stream>>>(tmp, qcw, qbuf);
    gemm_bb<<<gg, 256, 0, stream>>>(hsb, DD, kwb, DD, tmp, DD, DD);
    convnorm_qk_k<<<BL*HH, 256, 0, stream>>>(tmp, kcw, kbuf);
    gemm_bb<<<gg, 256, 0, stream>>>(hsb, DD, vwb, DD, tmp, DD, DD);
    conv_silu_k<<<(int)(BLD/256), 256, 0, stream>>>(tmp, vcw, vbuf);

    beta_k<<<BL, 256, 0, stream>>>(hs, bw, betab);

    tr_k<<<8*64*4, 256, 0, stream>>>(kbuf, ktbuf);
    // chunk_prep2 writes uT directly (tru_k eliminated)
    chunk_prep2_k<<<BB*HH*NC, 256, 0, stream>>>(qbuf, kbuf, ktbuf, vbuf, betab,
                                                uTbuf, wbuf, attnb);

    scan12_k<<<BB*HH*16, 256, 0, stream>>>(qbuf, ktbuf, uTbuf, wbuf, attnb, dbuf);

    fir2_k<5><<<BB*64*16, 256, 0, stream>>>(vbuf, fsw, lsbuf);
    fir2_k<64><<<BB*64*16, 256, 0, stream>>>(vbuf, flw, llbuf);

    stats_k<<<BL, 256, 0, stream>>>(lsbuf, llbuf, dbuf, vbuf, statsb);

    // hpart GEMM reads the pristine f32 input hs (hsb is dead: overwritten by dbuf)
    gemm_mfma<<<gg, 256, 0, stream>>>(hs, DD, w1, 1040, b1, hpart, DD, DD);
    gate_fin2_k<<<BL, 256, 0, stream>>>(hpart, statsb, w1sp, w2, b2, lt, fwbuf);

    combine_k<<<BL*HH, 256, 0, stream>>>(lsbuf, llbuf, dbuf, vbuf, fwbuf, rss, rsl, onw, opre);

    gemm_mfma<<<gg, 256, 0, stream>>>(opre, DD, opw, DD, nullptr, out, DD, DD);
}

// Round 8
// 807.309 us; speedup vs baseline: 1.0976x; 1.0976x over previous
//
#include <hip/hip_runtime.h>
#include <hip/hip_bf16.h>

#define BB 2
#define LL 4096
#define DD 1024
#define HH 4
#define DH 256
#define CH 32
#define NC (LL/CH)     // 128
#define BL (BB*LL)     // 8192
#define BLD ((size_t)BB*LL*DD) // 8388608

typedef __attribute__((ext_vector_type(8))) short short8;
typedef __attribute__((ext_vector_type(4))) float floatx4;

__device__ __forceinline__ float bf2f(unsigned short u) {
    union { float f; unsigned int i; } x; x.i = ((unsigned int)u) << 16; return x.f;
}
__device__ __forceinline__ float bflo(unsigned int u) {
    union { float f; unsigned int i; } x; x.i = u << 16; return x.f;
}
__device__ __forceinline__ float bfhi(unsigned int u) {
    union { float f; unsigned int i; } x; x.i = u & 0xFFFF0000u; return x.f;
}
__device__ __forceinline__ unsigned short f2bf(float f) {
    union { float f; unsigned int i; } x; x.f = f;
    unsigned int r = x.i + 0x7FFFu + ((x.i >> 16) & 1u);
    return (unsigned short)(r >> 16);
}
// pack two f32 -> (bf16(b)<<16)|bf16(a), round-half-up
__device__ __forceinline__ unsigned int pkbf(float a, float b) {
    unsigned int ua = __float_as_uint(a) + 0x8000u;
    unsigned int ub = __float_as_uint(b) + 0x8000u;
    return __builtin_amdgcn_perm(ub, ua, 0x07060302);
}
// barrier with LDS-only drain (no vmcnt drain -> pinned loads stay in flight)
__device__ __forceinline__ void lds_barrier() {
    __builtin_amdgcn_s_waitcnt(0xC07F);
    __builtin_amdgcn_s_barrier();
}
// asm-pinned global loads (r1-r3: plain-C prefetch gets sunk by the scheduler)
__device__ __forceinline__ short8 gload16(const void* p) {
    short8 r;
    asm volatile("global_load_dwordx4 %0, %1, off" : "=v"(r) : "v"(p) : "memory");
    return r;
}
__device__ __forceinline__ uint2 gload8(const void* p) {
    uint2 r;
    asm volatile("global_load_dwordx2 %0, %1, off" : "=v"(r) : "v"(p) : "memory");
    return r;
}

// ---------------------------------------------------------------- f32 -> bf16 bulk convert
__global__ __launch_bounds__(256) void cvt_bf_k(
    const float* __restrict__ x, unsigned short* __restrict__ y)
{
    size_t i = ((size_t)blockIdx.x * 256 + threadIdx.x) * 4;
    float4 v = *(const float4*)(x + i);
    ushort4 o;
    o.x = f2bf(v.x); o.y = f2bf(v.y); o.z = f2bf(v.z); o.w = f2bf(v.w);
    *(ushort4*)(y + i) = o;
}

// ---------------------------------------------------------------- pack w1[:,1024:1040] -> bf16 [1024][16]
__global__ __launch_bounds__(256) void w1s_prep_k(
    const float* __restrict__ w1, unsigned short* __restrict__ w1s)
{
    int idx = blockIdx.x * 256 + threadIdx.x;   // 16384
    int e = idx >> 4, s = idx & 15;
    w1s[idx] = f2bf(w1[(size_t)e * 1040 + 1024 + s]);
}

// ---------------------------------------------------------------- bf16 MFMA GEMM (NT), f32 A, f32 W
__global__ __launch_bounds__(256) void gemm_mfma(
    const float* __restrict__ A, int lda,
    const float* __restrict__ W, int ldw,
    const float* __restrict__ bias,
    float* __restrict__ C, int ldc, int K)
{
    __shared__ unsigned short Abuf[128][56];
    __shared__ unsigned short Bbuf[128][56];
    const int t = threadIdx.x;
    const int wave = t >> 6, lane = t & 63;
    const int wm = wave >> 1, wn = wave & 1;
    const int row0 = blockIdx.y * 128, col0 = blockIdx.x * 128;

    floatx4 acc[4][4];
#pragma unroll
    for (int i = 0; i < 4; ++i)
#pragma unroll
        for (int j = 0; j < 4; ++j) acc[i][j] = (floatx4){0.f, 0.f, 0.f, 0.f};

    const int fr = lane & 15, fk = (lane >> 4) * 8;

    for (int kt = 0; kt < K; kt += 32) {
        __syncthreads();
#pragma unroll
        for (int it = 0; it < 2; ++it) {
            int idx = t + it * 256;
            int r = idx >> 2, s = (idx & 3) * 8;
            const float* ap = A + (size_t)(row0 + r) * lda + kt + s;
            float4 a0 = *(const float4*)(ap);
            float4 a1 = *(const float4*)(ap + 4);
            ushort4 p0, p1;
            p0.x = f2bf(a0.x); p0.y = f2bf(a0.y); p0.z = f2bf(a0.z); p0.w = f2bf(a0.w);
            p1.x = f2bf(a1.x); p1.y = f2bf(a1.y); p1.z = f2bf(a1.z); p1.w = f2bf(a1.w);
            *(ushort4*)&Abuf[r][s]     = p0;
            *(ushort4*)&Abuf[r][s + 4] = p1;
            const float* wp = W + (size_t)(col0 + r) * ldw + kt + s;
            float4 b0 = *(const float4*)(wp);
            float4 b1 = *(const float4*)(wp + 4);
            ushort4 q0, q1;
            q0.x = f2bf(b0.x); q0.y = f2bf(b0.y); q0.z = f2bf(b0.z); q0.w = f2bf(b0.w);
            q1.x = f2bf(b1.x); q1.y = f2bf(b1.y); q1.z = f2bf(b1.z); q1.w = f2bf(b1.w);
            *(ushort4*)&Bbuf[r][s]     = q0;
            *(ushort4*)&Bbuf[r][s + 4] = q1;
        }
        __syncthreads();

        short8 afrag[4], bfrag[4];
#pragma unroll
        for (int i = 0; i < 4; ++i) {
            afrag[i] = *(const short8*)&Abuf[wm * 64 + i * 16 + fr][fk];
            bfrag[i] = *(const short8*)&Bbuf[wn * 64 + i * 16 + fr][fk];
        }
#pragma unroll
        for (int i = 0; i < 4; ++i)
#pragma unroll
            for (int j = 0; j < 4; ++j)
                acc[i][j] = __builtin_amdgcn_mfma_f32_16x16x32_bf16(
                    afrag[i], bfrag[j], acc[i][j], 0, 0, 0);
    }

    const int fc = lane & 15, frow = (lane >> 4) * 4;
#pragma unroll
    for (int j = 0; j < 4; ++j) {
        int col = col0 + wn * 64 + j * 16 + fc;
        float bv = bias ? bias[col] : 0.0f;
#pragma unroll
        for (int i = 0; i < 4; ++i) {
#pragma unroll
            for (int r = 0; r < 4; ++r) {
                int row = row0 + wm * 64 + i * 16 + frow + r;
                C[(size_t)row * ldc + col] = acc[i][j][r] + bv;
            }
        }
    }
}

// ---------------------------------------------------------------- bf16 MFMA GEMM (NT), bf16 A, bf16 B
__global__ __launch_bounds__(256) void gemm_bb(
    const unsigned short* __restrict__ A, int lda,
    const unsigned short* __restrict__ B, int ldb,
    float* __restrict__ C, int ldc, int K)
{
    __shared__ unsigned short Abuf[128][56];
    __shared__ unsigned short Bbuf[128][56];
    const int t = threadIdx.x;
    const int wave = t >> 6, lane = t & 63;
    const int wm = wave >> 1, wn = wave & 1;
    const int row0 = blockIdx.y * 128, col0 = blockIdx.x * 128;

    floatx4 acc[4][4];
#pragma unroll
    for (int i = 0; i < 4; ++i)
#pragma unroll
        for (int j = 0; j < 4; ++j) acc[i][j] = (floatx4){0.f, 0.f, 0.f, 0.f};

    const int fr = lane & 15, fk = (lane >> 4) * 8;

    for (int kt = 0; kt < K; kt += 32) {
        __syncthreads();
#pragma unroll
        for (int it = 0; it < 2; ++it) {
            int idx = t + it * 256;
            int r = idx >> 2, s = (idx & 3) * 8;
            uint4 av = *(const uint4*)(A + (size_t)(row0 + r) * lda + kt + s);
            *(uint4*)&Abuf[r][s] = av;
            uint4 bv = *(const uint4*)(B + (size_t)(col0 + r) * ldb + kt + s);
            *(uint4*)&Bbuf[r][s] = bv;
        }
        __syncthreads();

        short8 afrag[4], bfrag[4];
#pragma unroll
        for (int i = 0; i < 4; ++i) {
            afrag[i] = *(const short8*)&Abuf[wm * 64 + i * 16 + fr][fk];
            bfrag[i] = *(const short8*)&Bbuf[wn * 64 + i * 16 + fr][fk];
        }
#pragma unroll
        for (int i = 0; i < 4; ++i)
#pragma unroll
            for (int j = 0; j < 4; ++j)
                acc[i][j] = __builtin_amdgcn_mfma_f32_16x16x32_bf16(
                    afrag[i], bfrag[j], acc[i][j], 0, 0, 0);
    }

    const int fc = lane & 15, frow = (lane >> 4) * 4;
#pragma unroll
    for (int j = 0; j < 4; ++j) {
        int col = col0 + wn * 64 + j * 16 + fc;
#pragma unroll
        for (int i = 0; i < 4; ++i) {
#pragma unroll
            for (int r = 0; r < 4; ++r) {
                int row = row0 + wm * 64 + i * 16 + frow + r;
                C[(size_t)row * ldc + col] = acc[i][j][r];
            }
        }
    }
}

// --------------------------------------- causal dwconv K=4 + silu + head-l2norm -> bf16
__global__ __launch_bounds__(256) void convnorm_qk_k(
    const float* __restrict__ x, const float* __restrict__ w,
    unsigned short* __restrict__ y)
{
    int bl = blockIdx.x >> 2;
    int h  = blockIdx.x & 3;
    int l  = bl & (LL - 1);
    int d  = threadIdx.x;
    int c  = h * DH + d;
    const float* wp = w + (size_t)c * 4;
    const float* xp = x + (size_t)bl * DD + c;
    float acc = wp[3] * xp[0];
    if (l >= 1) acc += wp[2] * xp[-(int)DD];
    if (l >= 2) acc += wp[1] * xp[-2*(int)DD];
    if (l >= 3) acc += wp[0] * xp[-3*(int)DD];
    acc = acc / (1.0f + expf(-acc));
    float s = acc * acc;
#pragma unroll
    for (int off = 32; off > 0; off >>= 1) s += __shfl_down(s, off);
    __shared__ float red[4];
    int wv = threadIdx.x >> 6, ln = threadIdx.x & 63;
    if (ln == 0) red[wv] = s;
    __syncthreads();
    float tot = red[0] + red[1] + red[2] + red[3];
    y[(size_t)bl * DD + c] = f2bf(acc * rsqrtf(tot));
}

// ------------------------------------------------- causal depthwise conv K=4 + silu (f32)
__global__ __launch_bounds__(256) void conv_silu_k(
    const float* __restrict__ x, const float* __restrict__ w, float* __restrict__ y)
{
    size_t idx = (size_t)blockIdx.x * 256 + threadIdx.x;
    int c = (int)(idx & (DD - 1));
    int bl = (int)(idx >> 10);
    int l = bl & (LL - 1);
    const float* wp = w + (size_t)c * 4;
    const float* xp = x + (size_t)bl * DD + c;
    float acc = wp[3] * xp[0];
    if (l >= 1) acc += wp[2] * xp[-(int)DD];
    if (l >= 2) acc += wp[1] * xp[-2*(int)DD];
    if (l >= 3) acc += wp[0] * xp[-3*(int)DD];
    y[idx] = acc / (1.0f + expf(-acc));
}

// ------------------------------------------------- FIR causal depthwise conv, LDS-tiled
template<int K>
__global__ __launch_bounds__(256) void fir2_k(
    const float* __restrict__ x, const float* __restrict__ filt, float* __restrict__ y)
{
    const int ctile = blockIdx.x & 15;
    const int ltile = (blockIdx.x >> 4) & 63;
    const int b = blockIdx.x >> 10;
    const int RT = 64 + K - 1;
    __shared__ float xs[RT][64];
    __shared__ float fs[64][K + 1];
    const int t = threadIdx.x;
    const int l0 = ltile * 64;

    for (int i = t; i < RT * 16; i += 256) {
        int li = i >> 4, c4 = (i & 15) * 4;
        int l = l0 - (K - 1) + li;
        float4 v = make_float4(0.f, 0.f, 0.f, 0.f);
        if (l >= 0)
            v = *(const float4*)(x + ((size_t)b * LL + l) * DD + ctile * 64 + c4);
        *(float4*)&xs[li][c4] = v;
    }
    for (int i = t; i < 64 * K; i += 256) {
        fs[i / K][i % K] = filt[(size_t)ctile * 64 * K + i];
    }
    __syncthreads();

    const int c = t & 63, lg = t >> 6;
    float acc[16];
#pragma unroll
    for (int o = 0; o < 16; ++o) acc[o] = 0.f;
#pragma unroll
    for (int j = 0; j < 16 + K - 1; ++j) {
        float xv = xs[lg * 16 + j][c];
#pragma unroll
        for (int o = 0; o < 16; ++o) {
            int tap = j - o;
            if (tap >= 0 && tap < K) acc[o] += fs[c][tap] * xv;
        }
    }
    size_t base = ((size_t)b * LL + l0 + lg * 16) * DD + ctile * 64 + c;
#pragma unroll
    for (int o = 0; o < 16; ++o)
        y[base + (size_t)o * DD] = acc[o];
}

// ------------------------------------------------- beta = sigmoid(hs @ b_proj^T)
__global__ __launch_bounds__(256) void beta_k(
    const float* __restrict__ hs, const float* __restrict__ bw, float* __restrict__ beta)
{
    int bl = blockIdx.x;
    const float* xr = hs + (size_t)bl * DD;
    float a0=0.f,a1=0.f,a2=0.f,a3=0.f;
    for (int k = threadIdx.x; k < DD; k += 256) {
        float xv = xr[k];
        a0 += xv * bw[k];
        a1 += xv * bw[DD + k];
        a2 += xv * bw[2*DD + k];
        a3 += xv * bw[3*DD + k];
    }
#pragma unroll
    for (int off = 32; off > 0; off >>= 1) {
        a0 += __shfl_down(a0, off); a1 += __shfl_down(a1, off);
        a2 += __shfl_down(a2, off); a3 += __shfl_down(a3, off);
    }
    __shared__ float red[4][4];
    int wv = threadIdx.x >> 6, ln = threadIdx.x & 63;
    if (ln == 0) { red[wv][0]=a0; red[wv][1]=a1; red[wv][2]=a2; red[wv][3]=a3; }
    __syncthreads();
    if (threadIdx.x < 4) {
        int h = threadIdx.x;
        float s = red[0][h] + red[1][h] + red[2][h] + red[3][h];
        beta[(size_t)bl * HH + h] = 1.0f / (1.0f + expf(-s));
    }
}

// ------------------------------------------------- chunk prep v3: MFMA everywhere +
// emits FRAGMENT-ORDERED TILED operand streams for the scan so every scan load is a
// contiguous 1KB (16 consecutive 64B lines) instead of a 16-line scatter:
//   qt/wt[bh][ci][half][kt][lr][lg][8]  (16KB/chunk each)
//   kTt  [bh][ci][wave][mt][lr][lg][8]  (16KB/chunk)
//   uTt  [bh][jb][ci][half][lr][lg][4]  (1KB/chunk per jb)
// kTt + w's B-operand are derived from the staged kL (tr_k kernel deleted).
__global__ __launch_bounds__(256) void chunk_prep3_k(
    const unsigned short* __restrict__ q, const unsigned short* __restrict__ k,
    const float* __restrict__ v, const float* __restrict__ beta,
    unsigned short* __restrict__ qt, unsigned short* __restrict__ kTt,
    unsigned short* __restrict__ wt, unsigned short* __restrict__ uTt,
    unsigned short* __restrict__ attn_out)
{
    const int ci = blockIdx.x & (NC - 1);
    const int bh = blockIdx.x >> 7;
    const int h = bh & (HH - 1), b = bh >> 2;
    __shared__ unsigned short kL[32][264];
    __shared__ unsigned short qL[32][264];
    __shared__ float vL[32][260];
    __shared__ float AmL[32][33];
    __shared__ unsigned short AbH[32][40];
    __shared__ unsigned short AbL2[32][40];
    __shared__ float betL[32];
    const int t = threadIdx.x;
    const int wave = t >> 6, lane = t & 63;
    const int lr = lane & 15, lg = lane >> 4;
    const int l0 = ci * CH;
    const size_t rowbase = (size_t)b * LL + l0;

    // ---- phase 1: stage k,q (bf16, padded rows) + v (f32, padded) + beta
    for (int i = t; i < 1024; i += 256) {
        int r = i >> 5, s8 = (i & 31) * 8;
        *(uint4*)&kL[r][s8] = *(const uint4*)(k + (rowbase + r) * DD + h * DH + s8);
        *(uint4*)&qL[r][s8] = *(const uint4*)(q + (rowbase + r) * DD + h * DH + s8);
    }
    for (int i = t; i < 2048; i += 256) {
        int e = i >> 6, d4 = (i & 63) * 4;
        *(float4*)&vL[e][d4] = *(const float4*)(v + (rowbase + e) * DD + h * DH + d4);
    }
    if (t < 32) betL[t] = beta[(rowbase + t) * HH + h];
    __syncthreads();

    // ---- phase 2: per-wave 16x16 tile of Am (k k^T) and attn (q k^T), K=256
    const int mt = wave >> 1, nt = wave & 1;
    floatx4 accA = (floatx4){0.f,0.f,0.f,0.f}, accT = accA;
#pragma unroll
    for (int ks = 0; ks < 8; ++ks) {
        short8 bk = *(const short8*)&kL[nt * 16 + lr][ks * 32 + lg * 8];
        short8 ak = *(const short8*)&kL[mt * 16 + lr][ks * 32 + lg * 8];
        short8 aq = *(const short8*)&qL[mt * 16 + lr][ks * 32 + lg * 8];
        accA = __builtin_amdgcn_mfma_f32_16x16x32_bf16(ak, bk, accA, 0, 0, 0);
        accT = __builtin_amdgcn_mfma_f32_16x16x32_bf16(aq, bk, accT, 0, 0, 0);
    }
    {
        const size_t abase = (size_t)blockIdx.x * (CH * CH);
        const int ee = nt * 16 + lr;
#pragma unroll
        for (int r = 0; r < 4; ++r) {
            int c = mt * 16 + lg * 4 + r;
            float bc = betL[c];
            AmL[c][ee] = (ee < c) ? (-bc * accA[r]) : 0.0f;
            attn_out[abase + (size_t)c * CH + ee] =
                (ee <= c) ? f2bf(accT[r]) : (unsigned short)0;
        }
    }
    __syncthreads();

    // ---- phase 3: wave 0 substitution; waves 1-3 copy qt + kTt tiles (dense stores)
    unsigned short* qtc  = qt  + (size_t)blockIdx.x * 8192;
    unsigned short* kTtc = kTt + (size_t)blockIdx.x * 8192;
    if (wave == 0) {
        const int j = lane & 31;
        float col[32];
#pragma unroll
        for (int c = 0; c < 32; ++c) col[c] = AmL[c][j];
#pragma unroll
        for (int i = 1; i < 32; ++i) {
            float u0 = 0.f, u1 = 0.f;
#pragma unroll
            for (int kk = 0; kk < 32; kk += 2) {
                if (kk < i)     u0 += __shfl(col[i], kk) * col[kk];
                if (kk + 1 < i) u1 += __shfl(col[i], kk + 1) * col[kk + 1];
            }
            if (j < i) col[i] += u0 + u1;
        }
        if (lane < 32) {
            const float bj = betL[j];
#pragma unroll
            for (int c = 0; c < 32; ++c) {
                float val = (col[c] + (c == j ? 1.0f : 0.0f)) * bj;
                unsigned short hi = f2bf(val);
                AbH[c][j] = hi;
                AbL2[c][j] = f2bf(val - bf2f(hi));
            }
        }
    } else {
        for (int o = t - 64; o < 2048; o += 192) {
            if (o < 1024) {
                int lg2 = o & 3, lr2 = (o >> 2) & 15, kt2 = (o >> 6) & 7, hf = o >> 9;
                short8 val = *(const short8*)&qL[hf * 16 + lr2][kt2 * 32 + lg2 * 8];
                *(short8*)(qtc + (size_t)o * 8) = val;
            } else {
                int o2 = o - 1024;
                int lg2 = o2 & 3, lr2 = (o2 >> 2) & 15, mt2 = (o2 >> 6) & 3, wv = o2 >> 8;
                int e = wv * 64 + mt2 * 16 + lr2;
                union { short8 s8; unsigned short u[8]; } val;
#pragma unroll
                for (int j2 = 0; j2 < 8; ++j2) val.u[j2] = kL[lg2 * 8 + j2][e];
                *(short8*)(kTtc + (size_t)o2 * 8) = val.s8;
            }
        }
    }
    __syncthreads();

    // ---- phase 4: u (tiled, direct to uTt) and w (tiled wt). Dual-bf16 Ab.
    short8 AH[2], ALo[2];
#pragma unroll
    for (int m = 0; m < 2; ++m) {
        AH[m]  = *(const short8*)&AbH[m * 16 + lr][lg * 8];
        ALo[m] = *(const short8*)&AbL2[m * 16 + lr][lg * 8];
    }
    unsigned short* wtc = wt + (size_t)blockIdx.x * 8192;
#pragma unroll
    for (int n = 0; n < 4; ++n) {
        const int d = wave * 64 + n * 16 + lr;
        union { short8 s8; unsigned int u[4]; } vf;
#pragma unroll
        for (int p2 = 0; p2 < 4; ++p2)
            vf.u[p2] = pkbf(vL[lg * 8 + p2 * 2][d], vL[lg * 8 + p2 * 2 + 1][d]);
        union { short8 s8; unsigned short u[8]; } wBv;
#pragma unroll
        for (int j2 = 0; j2 < 8; ++j2) wBv.u[j2] = kL[lg * 8 + j2][d];

        const int jb2 = wave * 4 + n;
        unsigned short* utc = uTt + ((size_t)(bh * 16 + jb2) * NC + ci) * 512;
#pragma unroll
        for (int m = 0; m < 2; ++m) {
            floatx4 au = (floatx4){0.f,0.f,0.f,0.f};
            au = __builtin_amdgcn_mfma_f32_16x16x32_bf16(AH[m],  vf.s8, au, 0, 0, 0);
            au = __builtin_amdgcn_mfma_f32_16x16x32_bf16(ALo[m], vf.s8, au, 0, 0, 0);
            ushort4 ou;
            ou.x = f2bf(au[0]); ou.y = f2bf(au[1]); ou.z = f2bf(au[2]); ou.w = f2bf(au[3]);
            *(ushort4*)(utc + m * 256 + lr * 16 + lg * 4) = ou;

            floatx4 aw = (floatx4){0.f,0.f,0.f,0.f};
            aw = __builtin_amdgcn_mfma_f32_16x16x32_bf16(AH[m],  wBv.s8, aw, 0, 0, 0);
            aw = __builtin_amdgcn_mfma_f32_16x16x32_bf16(ALo[m], wBv.s8, aw, 0, 0, 0);
#pragma unroll
            for (int r = 0; r < 4; ++r) {
                // wt[half=m][kt=d>>5][lr=lg*4+r][lg2=(d>>3)&3][j=d&7]
                int off = m * 4096 + (d >> 5) * 512 + (lg * 4 + r) * 32
                          + ((d >> 3) & 3) * 8 + (d & 7);
                wtc[off] = f2bf(aw[r]);
            }
        }
    }
}

// ------------------------------------------------- chunk scan v13: scan12 skeleton
// (asm-pinned prefetch, counted vmcnt(13|17), 2 LDS-only barriers) but ALL loads are
// now dense contiguous streams from the tiled operand layouts: each load touches 16
// CONSECUTIVE 64B lines (r6 diagnosis: the per-CU wall is TCP line processing of
// scattered 16-line loads, ~4cy/line; dense streams run 2-3x faster per m56).
__global__ __launch_bounds__(256, 1) void scan13_k(
    const unsigned short* __restrict__ qt, const unsigned short* __restrict__ kTt,
    const unsigned short* __restrict__ uTt, const unsigned short* __restrict__ wt,
    const unsigned short* __restrict__ attn, float* __restrict__ dout)
{
    const int bh = blockIdx.x & 7;     // low bits -> 16 same-bh blocks share one XCD
    const int jb = blockIdx.x >> 3;
    const int jcol = jb * 16;
    const int wave = threadIdx.x >> 6, lane = threadIdx.x & 63;
    const int lr = lane & 15, lg = lane >> 4;
    const int half = wave & 1;
    const bool isQ = wave >= 2;

    __shared__ unsigned short SbT[16][264];    // [col][e] bf16 (single buffer)
    __shared__ unsigned short uadjT[16][40];   // [col][cc] bf16 (single buffer)

    floatx4 Sacc[4];
#pragma unroll
    for (int mtv = 0; mtv < 4; ++mtv) Sacc[mtv] = (floatx4){0.f,0.f,0.f,0.f};

    // dense tiled stream bases (per-lane constant part folded in)
    const unsigned short* potb = (isQ ? qt : wt) + (size_t)bh * NC * 8192
                                 + half * 4096 + lr * 32 + lg * 8;
    const unsigned short* kttb = kTt + (size_t)bh * NC * 8192
                                 + wave * 2048 + lr * 32 + lg * 8;
    const unsigned short* uttb = uTt + (size_t)(bh * 16 + jb) * NC * 512
                                 + half * 256 + lr * 16 + lg * 4;
    const unsigned short* atb  = attn + (size_t)bh * NC * 1024
                                 + (half * 16 + lr) * 32 + lg * 8;
    float* db = dout + (size_t)bh * LL * DH;

    short8 po[2][8];     // this wave's A rows (w or q), K=256
    short8 pk[2][4];     // kT A-frags for S-update
    short8 pa[2];        // attn frag (waves 2,3)
    uint2  pu[2];        // u elems (waves 0,1)

    // 13 pinned loads for chunk cn into register slot s (uniform count all waves)
#define ISSUE13(cn, s)                                                          \
    {                                                                           \
        const size_t co_ = (size_t)(cn) * 8192;                                 \
        po[s][0] = gload16(potb + co_ + 0*512);                                 \
        po[s][1] = gload16(potb + co_ + 1*512);                                 \
        po[s][2] = gload16(potb + co_ + 2*512);                                 \
        po[s][3] = gload16(potb + co_ + 3*512);                                 \
        po[s][4] = gload16(potb + co_ + 4*512);                                 \
        po[s][5] = gload16(potb + co_ + 5*512);                                 \
        po[s][6] = gload16(potb + co_ + 6*512);                                 \
        po[s][7] = gload16(potb + co_ + 7*512);                                 \
        pk[s][0] = gload16(kttb + co_ + 0*512);                                 \
        pk[s][1] = gload16(kttb + co_ + 1*512);                                 \
        pk[s][2] = gload16(kttb + co_ + 2*512);                                 \
        pk[s][3] = gload16(kttb + co_ + 3*512);                                 \
        if (!isQ) pu[s] = gload8(uttb + (size_t)(cn) * 512);                    \
        else      pa[s] = gload16(atb + (size_t)(cn) * 1024);                   \
    }

    // prologue: pin chunk 0's loads -> slot 0
    ISSUE13(0, 0);

#pragma unroll 2
    for (int ci = 0; ci < NC; ++ci) {
        const int p = ci & 1;
        const int l0 = ci * CH;

        // 1) issue pinned loads for chunk ci+1 (clamped tail keeps counts uniform)
        {
            const int cn = (ci + 1 < NC) ? (ci + 1) : ci;
            ISSUE13(cn, p ^ 1);
        }

        // 2) pack wave's S e-slice -> SbT
#pragma unroll
        for (int mtv = 0; mtv < 4; ++mtv) {
            int e0 = 64 * wave + 16 * mtv + lg * 4;
            *(uint2*)&SbT[lr][e0] = make_uint2(pkbf(Sacc[mtv][0], Sacc[mtv][1]),
                                               pkbf(Sacc[mtv][2], Sacc[mtv][3]));
        }
        lds_barrier();   // (a) SbT published; uadjT reads of ci-1 closed

        // 3) counted drain: exactly chunk ci's 13 loads; ci+1's stay in flight.
        if (!isQ || ci == 0) { asm volatile("s_waitcnt vmcnt(13)" ::: "memory"); }
        else                 { asm volatile("s_waitcnt vmcnt(17)" ::: "memory"); }
        __builtin_amdgcn_sched_barrier(0);

        // 4) P = A @ S over full K=256 (two independent chains for ILP)
        floatx4 Pa = (floatx4){0.f,0.f,0.f,0.f}, Pb = Pa;
#pragma unroll
        for (int kt = 0; kt < 4; ++kt) {
            short8 s0 = *(const short8*)&SbT[lr][(2*kt)   * 32 + lg * 8];
            short8 s1 = *(const short8*)&SbT[lr][(2*kt+1) * 32 + lg * 8];
            Pa = __builtin_amdgcn_mfma_f32_16x16x32_bf16(po[p][2*kt],   s0, Pa, 0,0,0);
            Pb = __builtin_amdgcn_mfma_f32_16x16x32_bf16(po[p][2*kt+1], s1, Pb, 0,0,0);
        }
        floatx4 P = Pa + Pb;

        // 5) waves 0,1: uadj = u - w@S -> uadjT
        if (!isQ) {
            float ua0 = bflo(pu[p].x) - P[0];
            float ua1 = bfhi(pu[p].x) - P[1];
            float ua2 = bflo(pu[p].y) - P[2];
            float ua3 = bfhi(pu[p].y) - P[3];
            int cc0 = half * 16 + lg * 4;
            *(uint2*)&uadjT[lr][cc0] = make_uint2(pkbf(ua0, ua1), pkbf(ua2, ua3));
        }
        lds_barrier();   // (b) uadjT visible; SbT reads of this chunk closed

        short8 ub = *(const short8*)&uadjT[lr][lg * 8];

        // 6) waves 2,3: O = q@S + attn@uadj -> dout (4 stores/chunk, counted above)
        if (isQ) {
            floatx4 Ot = __builtin_amdgcn_mfma_f32_16x16x32_bf16(pa[p], ub, P, 0,0,0);
#pragma unroll
            for (int r = 0; r < 4; ++r)
                db[(size_t)(l0 + half * 16 + lg * 4 + r) * DH + jcol + lr] = Ot[r];
        }

        // 7) S e-slice += kT @ uadj
#pragma unroll
        for (int mtv = 0; mtv < 4; ++mtv)
            Sacc[mtv] = __builtin_amdgcn_mfma_f32_16x16x32_bf16(pk[p][mtv], ub, Sacc[mtv], 0,0,0);
    }
#undef ISSUE13
}

// ------------------------------------------------- per-head stats
__global__ __launch_bounds__(256) void stats_k(
    const float* __restrict__ ls, const float* __restrict__ llb,
    const float* __restrict__ dox, const float* __restrict__ v,
    float* __restrict__ stats)
{
    int bl = blockIdx.x;
    int b = bl >> 12, l = bl & (LL - 1);
    int wv = threadIdx.x >> 6, ln = threadIdx.x & 63;
    size_t ibase = (size_t)bl * DD + wv * DH;
    size_t dbase = (((size_t)(b * HH + wv)) * LL + l) * DH;
#pragma unroll
    for (int tn = 0; tn < 4; ++tn) {
        const float* p; size_t base;
        if (tn == 0)      { p = ls;  base = ibase; }
        else if (tn == 1) { p = llb; base = ibase; }
        else if (tn == 2) { p = dox; base = dbase; }
        else              { p = v;   base = ibase; }
        float4 x = *(const float4*)(p + base + ln * 4);
        float sm = x.x + x.y + x.z + x.w;
        float sq = x.x*x.x + x.y*x.y + x.z*x.z + x.w*x.w;
        float sa = fabsf(x.x) + fabsf(x.y) + fabsf(x.z) + fabsf(x.w);
#pragma unroll
        for (int off = 32; off > 0; off >>= 1) {
            sm += __shfl_down(sm, off);
            sq += __shfl_down(sq, off);
            sa += __shfl_down(sa, off);
        }
        if (ln == 0) {
            float mean = sm * (1.0f / DH);
            float var = sq * (1.0f / DH) - mean * mean;
            float am = sa * (1.0f / DH);
            float l2 = sqrtf(sq);
            *(float4*)(stats + (size_t)bl * 64 + wv * 16 + tn * 4) =
                make_float4(mean, var, am, l2);
        }
    }
}

// ------------------------------------------------- gate finish v2
__global__ __launch_bounds__(256) void gate_fin2_k(
    const float* __restrict__ hpart, const float* __restrict__ stats,
    const unsigned short* __restrict__ w1s,
    const float* __restrict__ w2, const float* __restrict__ b2,
    const float* __restrict__ ltemp, float* __restrict__ fw)
{
    const int bl = blockIdx.x;
    const int t = threadIdx.x;
    const float temp = log1pf(expf(ltemp[0])) + 1e-4f;
    __shared__ float st[HH][16];
    __shared__ float red[4][16];
    __shared__ float fin[16];
    if (t < 64) st[t >> 4][t & 15] = stats[(size_t)bl * 64 + t];

    const int e0 = t * 4;
    float4 hp4 = *(const float4*)(hpart + (size_t)bl * DD + e0);
    float hp[4] = {hp4.x, hp4.y, hp4.z, hp4.w};
    float w2a[4][4];
#pragma unroll
    for (int j = 0; j < 4; ++j) {
        float4 wv = *(const float4*)(w2 + (size_t)j * 1024 + e0);
        w2a[j][0] = wv.x; w2a[j][1] = wv.y; w2a[j][2] = wv.z; w2a[j][3] = wv.w;
    }
    uint4 wpk[8];
    const uint4* wp = (const uint4*)(w1s + (size_t)e0 * 16);
#pragma unroll
    for (int i = 0; i < 8; ++i) wpk[i] = wp[i];
    __syncthreads();

    float lg[4][4];
#pragma unroll
    for (int h = 0; h < 4; ++h)
#pragma unroll
        for (int j = 0; j < 4; ++j) lg[h][j] = 0.0f;

#pragma unroll
    for (int ii = 0; ii < 4; ++ii) {
        float xh[4] = {hp[ii], hp[ii], hp[ii], hp[ii]};
        unsigned arr[8] = {wpk[ii*2].x, wpk[ii*2].y, wpk[ii*2].z, wpk[ii*2].w,
                           wpk[ii*2+1].x, wpk[ii*2+1].y, wpk[ii*2+1].z, wpk[ii*2+1].w};
#pragma unroll
        for (int p = 0; p < 8; ++p) {
            float wlo = bflo(arr[p]), whi = bfhi(arr[p]);
            int s = p * 2;
#pragma unroll
            for (int h = 0; h < 4; ++h)
                xh[h] += st[h][s] * wlo + st[h][s + 1] * whi;
        }
#pragma unroll
        for (int h = 0; h < 4; ++h) {
            float x = xh[h];
            float gct = 0.5f * x * (1.0f + erff(x * 0.70710678118654752f));
            lg[h][0] += gct * w2a[0][ii];
            lg[h][1] += gct * w2a[1][ii];
            lg[h][2] += gct * w2a[2][ii];
            lg[h][3] += gct * w2a[3][ii];
        }
    }

#pragma unroll
    for (int h = 0; h < 4; ++h)
#pragma unroll
        for (int j = 0; j < 4; ++j)
#pragma unroll
            for (int off = 32; off > 0; off >>= 1)
                lg[h][j] += __shfl_down(lg[h][j], off);

    const int wv = t >> 6, ln = t & 63;
    if (ln == 0) {
#pragma unroll
        for (int h = 0; h < 4; ++h)
#pragma unroll
            for (int j = 0; j < 4; ++j) red[wv][h * 4 + j] = lg[h][j];
    }
    __syncthreads();
    if (t < 16) {
        float s = red[0][t] + red[1][t] + red[2][t] + red[3][t] + b2[t & 3];
        fin[t] = s / temp;
    }
    __syncthreads();
    if (t < 4) {
        float l0 = fin[t*4], l1 = fin[t*4+1], l2 = fin[t*4+2], l3 = fin[t*4+3];
        float m = fmaxf(fmaxf(l0, l1), fmaxf(l2, l3));
        float e0x = expf(l0-m), e1 = expf(l1-m), e2 = expf(l2-m), e3 = expf(l3-m);
        float inv = 1.0f / (e0x + e1 + e2 + e3);
        *(float4*)(fw + (size_t)bl * 16 + t * 4) = make_float4(e0x*inv, e1*inv, e2*inv, e3*inv);
    }
}

// ------------------------------------------------- combine + rms norm
__global__ __launch_bounds__(256) void combine_k(
    const float* __restrict__ ls, const float* __restrict__ llb,
    const float* __restrict__ dox, const float* __restrict__ v,
    const float* __restrict__ fw, const float* __restrict__ rss,
    const float* __restrict__ rsl, const float* __restrict__ onw,
    float* __restrict__ opre)
{
    int h = blockIdx.x & (HH - 1);
    int bl = blockIdx.x >> 2;
    int b = bl >> 12, l = bl & (LL - 1);
    int d = threadIdx.x;
    size_t i1 = (size_t)blockIdx.x * DH + d;
    size_t i2 = (((size_t)(b * HH + h)) * LL + l) * DH + d;
    const float* fwp = fw + (size_t)blockIdx.x * 4;
    float f0 = fwp[0], f1 = fwp[1], f2 = fwp[2], f3 = fwp[3];
    float aS = rss[0], aL = rsl[0];
    float vls = ls[i1], vll = llb[i1], vd = dox[i2], vv = v[i1];
    float o = f0*vls + f1*vll + f2*vd + f3*vv + aS*vls + aL*vll;
    float s = o * o;
#pragma unroll
    for (int off = 32; off > 0; off >>= 1) s += __shfl_down(s, off);
    __shared__ float red[4];
    int wv = threadIdx.x >> 6, ln = threadIdx.x & 63;
    if (ln == 0) red[wv] = s;
    __syncthreads();
    float ms = (red[0] + red[1] + red[2] + red[3]) * (1.0f / DH);
    opre[(size_t)bl * DD + h * DH + d] = o * rsqrtf(ms + 1e-5f) * onw[d];
}

// ================================================================ launch
extern "C" void kernel_launch(void* const* d_in, const int* in_sizes, int n_in,
                              void* d_out, int out_size, void* d_ws, size_t ws_size,
                              hipStream_t stream)
{
    const float* hs  = (const float*)d_in[0];
    const float* qw  = (const float*)d_in[1];
    const float* kw  = (const float*)d_in[2];
    const float* vw  = (const float*)d_in[3];
    const float* bw  = (const float*)d_in[4];
    const float* qcw = (const float*)d_in[5];
    const float* kcw = (const float*)d_in[6];
    const float* vcw = (const float*)d_in[7];
    const float* fsw = (const float*)d_in[8];
    const float* flw = (const float*)d_in[9];
    const float* w1  = (const float*)d_in[10];
    const float* b1  = (const float*)d_in[11];
    const float* w2  = (const float*)d_in[12];
    const float* b2  = (const float*)d_in[13];
    const float* lt  = (const float*)d_in[14];
    const float* rss = (const float*)d_in[15];
    const float* rsl = (const float*)d_in[16];
    const float* onw = (const float*)d_in[17];
    const float* opw = (const float*)d_in[18];
    float* out = (float*)d_out;

    float* wsf = (float*)d_ws;
    float* tmp   = wsf;
    // tiled scan operand streams (written by chunk_prep3 AFTER the projection phase,
    // so tmp doubles as the projection-GEMM scratch during phase 1 -- r7's bug was
    // moving that scratch onto vbuf and running conv_silu in place = cross-block race):
    unsigned short* kTtb = (unsigned short*)tmp;                  // 16MB (8*128*16KB)
    unsigned short* uTtb = (unsigned short*)(wsf + BLD/2);        // 16MB (8*16*128*1KB)
    float* vbuf  = wsf + BLD;
    float* dbuf  = wsf + 2*BLD;
    // hsb shares the dbuf region -> DEAD once scan13 writes dbuf. Only used in phase 1.
    unsigned short* hsb = (unsigned short*)(wsf + 2*BLD);
    // bf16 QKV weights live in the dead second half of the dbuf region during phase 1
    unsigned short* qwb = (unsigned short*)(wsf + 2*BLD + BLD/2);
    unsigned short* kwb = qwb + (size_t)DD*DD;
    unsigned short* vwb = kwb + (size_t)DD*DD;
    unsigned short* qbuf = (unsigned short*)(wsf + 3*BLD);
    unsigned short* kbuf = qbuf + BLD;
    float* hpart = wsf + 3*BLD;
    float* opre  = wsf + 3*BLD;
    unsigned short* qtb = (unsigned short*)(wsf + 4*BLD);         // 16MB tiled q
    unsigned short* wtb = qtb + BLD;                              // 16MB tiled w
    float* llbuf = wsf + 4*BLD;   // overlaps qtb/wtb: written only after scan consumed them
    float* lsbuf = tmp;           // overlaps kTtb/uTtb: written only after scan
    unsigned short* attnb = (unsigned short*)(wsf + 5*BLD);
    float* statsb = wsf + 5*BLD + 524288;
    float* fwbuf  = statsb + (size_t)BL*HH*16;
    float* betab  = fwbuf + (size_t)BL*HH*4;
    unsigned short* w1sp = (unsigned short*)(betab + (size_t)BL*HH);

    dim3 gg(8, 64);   // N/128, M/128

    cvt_bf_k<<<(int)(BLD/1024), 256, 0, stream>>>(hs, hsb);
    cvt_bf_k<<<1024, 256, 0, stream>>>(qw, qwb);
    cvt_bf_k<<<1024, 256, 0, stream>>>(kw, kwb);
    cvt_bf_k<<<1024, 256, 0, stream>>>(vw, vwb);
    w1s_prep_k<<<64, 256, 0, stream>>>(w1, w1sp);

    // projection GEMM scratch = tmp (wsf): dead after conv_silu, before chunk_prep3
    // writes kTtb/uTtb there. conv_silu reads tmp, writes vbuf (distinct) -- no race.
    gemm_bb<<<gg, 256, 0, stream>>>(hsb, DD, qwb, DD, tmp, DD, DD);
    convnorm_qk_k<<<BL*HH, 256, 0, stream>>>(tmp, qcw, qbuf);
    gemm_bb<<<gg, 256, 0, stream>>>(hsb, DD, kwb, DD, tmp, DD, DD);
    convnorm_qk_k<<<BL*HH, 256, 0, stream>>>(tmp, kcw, kbuf);
    gemm_bb<<<gg, 256, 0, stream>>>(hsb, DD, vwb, DD, tmp, DD, DD);
    conv_silu_k<<<(int)(BLD/256), 256, 0, stream>>>(tmp, vcw, vbuf);

    beta_k<<<BL, 256, 0, stream>>>(hs, bw, betab);

    // chunk_prep3 emits tiled qt/kTt/wt/uTt + attn (tr_k and tru_k eliminated)
    chunk_prep3_k<<<BB*HH*NC, 256, 0, stream>>>(qbuf, kbuf, vbuf, betab,
                                                qtb, kTtb, wtb, uTtb, attnb);

    scan13_k<<<BB*HH*16, 256, 0, stream>>>(qtb, kTtb, uTtb, wtb, attnb, dbuf);

    fir2_k<5><<<BB*64*16, 256, 0, stream>>>(vbuf, fsw, lsbuf);
    fir2_k<64><<<BB*64*16, 256, 0, stream>>>(vbuf, flw, llbuf);

    stats_k<<<BL, 256, 0, stream>>>(lsbuf, llbuf, dbuf, vbuf, statsb);

    // hpart GEMM reads the pristine f32 input hs (hsb is dead: overwritten by dbuf)
    gemm_mfma<<<gg, 256, 0, stream>>>(hs, DD, w1, 1040, b1, hpart, DD, DD);
    gate_fin2_k<<<BL, 256, 0, stream>>>(hpart, statsb, w1sp, w2, b2, lt, fwbuf);

    combine_k<<<BL*HH, 256, 0, stream>>>(lsbuf, llbuf, dbuf, vbuf, fwbuf, rss, rsl, onw, opre);

    gemm_mfma<<<gg, 256, 0, stream>>>(opre, DD, opw, DD, nullptr, out, DD, DD);
}

// Round 9
// 795.648 us; speedup vs baseline: 1.1137x; 1.0147x over previous
//
#include <hip/hip_runtime.h>
#include <hip/hip_bf16.h>

#define BB 2
#define LL 4096
#define DD 1024
#define HH 4
#define DH 256
#define CH 32
#define NC (LL/CH)     // 128
#define BL (BB*LL)     // 8192
#define BLD ((size_t)BB*LL*DD) // 8388608

typedef __attribute__((ext_vector_type(8))) short short8;
typedef __attribute__((ext_vector_type(4))) float floatx4;

__device__ __forceinline__ float bf2f(unsigned short u) {
    union { float f; unsigned int i; } x; x.i = ((unsigned int)u) << 16; return x.f;
}
__device__ __forceinline__ float bflo(unsigned int u) {
    union { float f; unsigned int i; } x; x.i = u << 16; return x.f;
}
__device__ __forceinline__ float bfhi(unsigned int u) {
    union { float f; unsigned int i; } x; x.i = u & 0xFFFF0000u; return x.f;
}
__device__ __forceinline__ unsigned short f2bf(float f) {
    union { float f; unsigned int i; } x; x.f = f;
    unsigned int r = x.i + 0x7FFFu + ((x.i >> 16) & 1u);
    return (unsigned short)(r >> 16);
}
// pack two f32 -> (bf16(b)<<16)|bf16(a), round-half-up
__device__ __forceinline__ unsigned int pkbf(float a, float b) {
    unsigned int ua = __float_as_uint(a) + 0x8000u;
    unsigned int ub = __float_as_uint(b) + 0x8000u;
    return __builtin_amdgcn_perm(ub, ua, 0x07060302);
}
// barrier with LDS-only drain (no vmcnt drain -> pinned loads stay in flight)
__device__ __forceinline__ void lds_barrier() {
    __builtin_amdgcn_s_waitcnt(0xC07F);
    __builtin_amdgcn_s_barrier();
}
// asm-pinned global loads (r1-r3: plain-C prefetch gets sunk by the scheduler)
__device__ __forceinline__ short8 gload16(const void* p) {
    short8 r;
    asm volatile("global_load_dwordx4 %0, %1, off" : "=v"(r) : "v"(p) : "memory");
    return r;
}
__device__ __forceinline__ uint2 gload8(const void* p) {
    uint2 r;
    asm volatile("global_load_dwordx2 %0, %1, off" : "=v"(r) : "v"(p) : "memory");
    return r;
}

// ---------------------------------------------------------------- f32 -> bf16 bulk convert
__global__ __launch_bounds__(256) void cvt_bf_k(
    const float* __restrict__ x, unsigned short* __restrict__ y)
{
    size_t i = ((size_t)blockIdx.x * 256 + threadIdx.x) * 4;
    float4 v = *(const float4*)(x + i);
    ushort4 o;
    o.x = f2bf(v.x); o.y = f2bf(v.y); o.z = f2bf(v.z); o.w = f2bf(v.w);
    *(ushort4*)(y + i) = o;
}

// ---------------------------------------------------------------- pack w1[:,1024:1040] -> bf16 [1024][16]
__global__ __launch_bounds__(256) void w1s_prep_k(
    const float* __restrict__ w1, unsigned short* __restrict__ w1s)
{
    int idx = blockIdx.x * 256 + threadIdx.x;   // 16384
    int e = idx >> 4, s = idx & 15;
    w1s[idx] = f2bf(w1[(size_t)e * 1040 + 1024 + s]);
}

// ---------------------------------------------------------------- bf16 MFMA GEMM (NT), f32 A, f32 W
__global__ __launch_bounds__(256) void gemm_mfma(
    const float* __restrict__ A, int lda,
    const float* __restrict__ W, int ldw,
    const float* __restrict__ bias,
    float* __restrict__ C, int ldc, int K)
{
    __shared__ unsigned short Abuf[128][56];
    __shared__ unsigned short Bbuf[128][56];
    const int t = threadIdx.x;
    const int wave = t >> 6, lane = t & 63;
    const int wm = wave >> 1, wn = wave & 1;
    const int row0 = blockIdx.y * 128, col0 = blockIdx.x * 128;

    floatx4 acc[4][4];
#pragma unroll
    for (int i = 0; i < 4; ++i)
#pragma unroll
        for (int j = 0; j < 4; ++j) acc[i][j] = (floatx4){0.f, 0.f, 0.f, 0.f};

    const int fr = lane & 15, fk = (lane >> 4) * 8;

    for (int kt = 0; kt < K; kt += 32) {
        __syncthreads();
#pragma unroll
        for (int it = 0; it < 2; ++it) {
            int idx = t + it * 256;
            int r = idx >> 2, s = (idx & 3) * 8;
            const float* ap = A + (size_t)(row0 + r) * lda + kt + s;
            float4 a0 = *(const float4*)(ap);
            float4 a1 = *(const float4*)(ap + 4);
            ushort4 p0, p1;
            p0.x = f2bf(a0.x); p0.y = f2bf(a0.y); p0.z = f2bf(a0.z); p0.w = f2bf(a0.w);
            p1.x = f2bf(a1.x); p1.y = f2bf(a1.y); p1.z = f2bf(a1.z); p1.w = f2bf(a1.w);
            *(ushort4*)&Abuf[r][s]     = p0;
            *(ushort4*)&Abuf[r][s + 4] = p1;
            const float* wp = W + (size_t)(col0 + r) * ldw + kt + s;
            float4 b0 = *(const float4*)(wp);
            float4 b1 = *(const float4*)(wp + 4);
            ushort4 q0, q1;
            q0.x = f2bf(b0.x); q0.y = f2bf(b0.y); q0.z = f2bf(b0.z); q0.w = f2bf(b0.w);
            q1.x = f2bf(b1.x); q1.y = f2bf(b1.y); q1.z = f2bf(b1.z); q1.w = f2bf(b1.w);
            *(ushort4*)&Bbuf[r][s]     = q0;
            *(ushort4*)&Bbuf[r][s + 4] = q1;
        }
        __syncthreads();

        short8 afrag[4], bfrag[4];
#pragma unroll
        for (int i = 0; i < 4; ++i) {
            afrag[i] = *(const short8*)&Abuf[wm * 64 + i * 16 + fr][fk];
            bfrag[i] = *(const short8*)&Bbuf[wn * 64 + i * 16 + fr][fk];
        }
#pragma unroll
        for (int i = 0; i < 4; ++i)
#pragma unroll
            for (int j = 0; j < 4; ++j)
                acc[i][j] = __builtin_amdgcn_mfma_f32_16x16x32_bf16(
                    afrag[i], bfrag[j], acc[i][j], 0, 0, 0);
    }

    const int fc = lane & 15, frow = (lane >> 4) * 4;
#pragma unroll
    for (int j = 0; j < 4; ++j) {
        int col = col0 + wn * 64 + j * 16 + fc;
        float bv = bias ? bias[col] : 0.0f;
#pragma unroll
        for (int i = 0; i < 4; ++i) {
#pragma unroll
            for (int r = 0; r < 4; ++r) {
                int row = row0 + wm * 64 + i * 16 + frow + r;
                C[(size_t)row * ldc + col] = acc[i][j][r] + bv;
            }
        }
    }
}

// ---------------------------------------------------------------- bf16 MFMA GEMM (NT), bf16 A/B, bf16 C
__global__ __launch_bounds__(256) void gemm_bb16(
    const unsigned short* __restrict__ A, int lda,
    const unsigned short* __restrict__ B, int ldb,
    unsigned short* __restrict__ C, int ldc, int K)
{
    __shared__ unsigned short Abuf[128][56];
    __shared__ unsigned short Bbuf[128][56];
    const int t = threadIdx.x;
    const int wave = t >> 6, lane = t & 63;
    const int wm = wave >> 1, wn = wave & 1;
    const int row0 = blockIdx.y * 128, col0 = blockIdx.x * 128;

    floatx4 acc[4][4];
#pragma unroll
    for (int i = 0; i < 4; ++i)
#pragma unroll
        for (int j = 0; j < 4; ++j) acc[i][j] = (floatx4){0.f, 0.f, 0.f, 0.f};

    const int fr = lane & 15, fk = (lane >> 4) * 8;

    for (int kt = 0; kt < K; kt += 32) {
        __syncthreads();
#pragma unroll
        for (int it = 0; it < 2; ++it) {
            int idx = t + it * 256;
            int r = idx >> 2, s = (idx & 3) * 8;
            uint4 av = *(const uint4*)(A + (size_t)(row0 + r) * lda + kt + s);
            *(uint4*)&Abuf[r][s] = av;
            uint4 bv = *(const uint4*)(B + (size_t)(col0 + r) * ldb + kt + s);
            *(uint4*)&Bbuf[r][s] = bv;
        }
        __syncthreads();

        short8 afrag[4], bfrag[4];
#pragma unroll
        for (int i = 0; i < 4; ++i) {
            afrag[i] = *(const short8*)&Abuf[wm * 64 + i * 16 + fr][fk];
            bfrag[i] = *(const short8*)&Bbuf[wn * 64 + i * 16 + fr][fk];
        }
#pragma unroll
        for (int i = 0; i < 4; ++i)
#pragma unroll
            for (int j = 0; j < 4; ++j)
                acc[i][j] = __builtin_amdgcn_mfma_f32_16x16x32_bf16(
                    afrag[i], bfrag[j], acc[i][j], 0, 0, 0);
    }

    const int fc = lane & 15, frow = (lane >> 4) * 4;
#pragma unroll
    for (int j = 0; j < 4; ++j) {
        int col = col0 + wn * 64 + j * 16 + fc;
#pragma unroll
        for (int i = 0; i < 4; ++i) {
#pragma unroll
            for (int r = 0; r < 4; ++r) {
                int row = row0 + wm * 64 + i * 16 + frow + r;
                C[(size_t)row * ldc + col] = f2bf(acc[i][j][r]);
            }
        }
    }
}

// --------------------------------------- causal dwconv K=4 + silu + head-l2norm (bf16 in) -> bf16
__global__ __launch_bounds__(256) void convnorm_qk_k(
    const unsigned short* __restrict__ x, const float* __restrict__ w,
    unsigned short* __restrict__ y)
{
    int bl = blockIdx.x >> 2;
    int h  = blockIdx.x & 3;
    int l  = bl & (LL - 1);
    int d  = threadIdx.x;
    int c  = h * DH + d;
    const float* wp = w + (size_t)c * 4;
    const unsigned short* xp = x + (size_t)bl * DD + c;
    float acc = wp[3] * bf2f(xp[0]);
    if (l >= 1) acc += wp[2] * bf2f(xp[-(int)DD]);
    if (l >= 2) acc += wp[1] * bf2f(xp[-2*(int)DD]);
    if (l >= 3) acc += wp[0] * bf2f(xp[-3*(int)DD]);
    acc = acc / (1.0f + expf(-acc));
    float s = acc * acc;
#pragma unroll
    for (int off = 32; off > 0; off >>= 1) s += __shfl_down(s, off);
    __shared__ float red[4];
    int wv = threadIdx.x >> 6, ln = threadIdx.x & 63;
    if (ln == 0) red[wv] = s;
    __syncthreads();
    float tot = red[0] + red[1] + red[2] + red[3];
    y[(size_t)bl * DD + c] = f2bf(acc * rsqrtf(tot));
}

// ------------------------------------------------- causal depthwise conv K=4 + silu (bf16 in, f32 out)
__global__ __launch_bounds__(256) void conv_silu_k(
    const unsigned short* __restrict__ x, const float* __restrict__ w, float* __restrict__ y)
{
    size_t idx = (size_t)blockIdx.x * 256 + threadIdx.x;
    int c = (int)(idx & (DD - 1));
    int bl = (int)(idx >> 10);
    int l = bl & (LL - 1);
    const float* wp = w + (size_t)c * 4;
    const unsigned short* xp = x + (size_t)bl * DD + c;
    float acc = wp[3] * bf2f(xp[0]);
    if (l >= 1) acc += wp[2] * bf2f(xp[-(int)DD]);
    if (l >= 2) acc += wp[1] * bf2f(xp[-2*(int)DD]);
    if (l >= 3) acc += wp[0] * bf2f(xp[-3*(int)DD]);
    y[idx] = acc / (1.0f + expf(-acc));
}

// ------------------------------------------------- FIR causal depthwise conv, LDS-tiled,
// v3: filter taps REGISTER-RESIDENT (thread's channel c is fixed -> its K taps are
// loop-invariant; the old fs[c][tap] LDS reads were 1264 ds_read_b32/thread for K=64,
// ~45us. Full static unroll keeps ft[] in VGPRs (rule #20), leaving only 79 xv reads).
template<int K>
__global__ __launch_bounds__(256) void fir3_k(
    const float* __restrict__ x, const float* __restrict__ filt, float* __restrict__ y)
{
    const int ctile = blockIdx.x & 15;
    const int ltile = (blockIdx.x >> 4) & 63;
    const int b = blockIdx.x >> 10;
    const int RT = 64 + K - 1;
    __shared__ float xs[RT][64];
    const int t = threadIdx.x;
    const int l0 = ltile * 64;

    for (int i = t; i < RT * 16; i += 256) {
        int li = i >> 4, c4 = (i & 15) * 4;
        int l = l0 - (K - 1) + li;
        float4 v = make_float4(0.f, 0.f, 0.f, 0.f);
        if (l >= 0)
            v = *(const float4*)(x + ((size_t)b * LL + l) * DD + ctile * 64 + c4);
        *(float4*)&xs[li][c4] = v;
    }
    const int c = t & 63, lg = t >> 6;
    float ft[K];
#pragma unroll
    for (int tap = 0; tap < K; ++tap)
        ft[tap] = filt[(size_t)(ctile * 64 + c) * K + tap];
    __syncthreads();

    float acc[16];
#pragma unroll
    for (int o = 0; o < 16; ++o) acc[o] = 0.f;
#pragma unroll
    for (int j = 0; j < 16 + K - 1; ++j) {
        float xv = xs[lg * 16 + j][c];
#pragma unroll
        for (int o = 0; o < 16; ++o) {
            int tap = j - o;
            if (tap >= 0 && tap < K) acc[o] += ft[tap] * xv;
        }
    }
    size_t base = ((size_t)b * LL + l0 + lg * 16) * DD + ctile * 64 + c;
#pragma unroll
    for (int o = 0; o < 16; ++o)
        y[base + (size_t)o * DD] = acc[o];
}

// ------------------------------------------------- beta = sigmoid(hs @ b_proj^T)
__global__ __launch_bounds__(256) void beta_k(
    const float* __restrict__ hs, const float* __restrict__ bw, float* __restrict__ beta)
{
    int bl = blockIdx.x;
    const float* xr = hs + (size_t)bl * DD;
    float a0=0.f,a1=0.f,a2=0.f,a3=0.f;
    for (int k = threadIdx.x; k < DD; k += 256) {
        float xv = xr[k];
        a0 += xv * bw[k];
        a1 += xv * bw[DD + k];
        a2 += xv * bw[2*DD + k];
        a3 += xv * bw[3*DD + k];
    }
#pragma unroll
    for (int off = 32; off > 0; off >>= 1) {
        a0 += __shfl_down(a0, off); a1 += __shfl_down(a1, off);
        a2 += __shfl_down(a2, off); a3 += __shfl_down(a3, off);
    }
    __shared__ float red[4][4];
    int wv = threadIdx.x >> 6, ln = threadIdx.x & 63;
    if (ln == 0) { red[wv][0]=a0; red[wv][1]=a1; red[wv][2]=a2; red[wv][3]=a3; }
    __syncthreads();
    if (threadIdx.x < 4) {
        int h = threadIdx.x;
        float s = red[0][h] + red[1][h] + red[2][h] + red[3][h];
        beta[(size_t)bl * HH + h] = 1.0f / (1.0f + expf(-s));
    }
}

// ------------------------------------------------- chunk prep v3: MFMA everywhere +
// emits FRAGMENT-ORDERED TILED operand streams for the scan (dense 1KB loads):
//   qt/wt[bh][ci][half][kt][lr][lg][8]  (16KB/chunk each)
//   kTt  [bh][ci][wave][mt][lr][lg][8]  (16KB/chunk)
//   uTt  [bh][jb][ci][half][lr][lg][4]  (1KB/chunk per jb)
__global__ __launch_bounds__(256) void chunk_prep3_k(
    const unsigned short* __restrict__ q, const unsigned short* __restrict__ k,
    const float* __restrict__ v, const float* __restrict__ beta,
    unsigned short* __restrict__ qt, unsigned short* __restrict__ kTt,
    unsigned short* __restrict__ wt, unsigned short* __restrict__ uTt,
    unsigned short* __restrict__ attn_out)
{
    const int ci = blockIdx.x & (NC - 1);
    const int bh = blockIdx.x >> 7;
    const int h = bh & (HH - 1), b = bh >> 2;
    __shared__ unsigned short kL[32][264];
    __shared__ unsigned short qL[32][264];
    __shared__ float vL[32][260];
    __shared__ float AmL[32][33];
    __shared__ unsigned short AbH[32][40];
    __shared__ unsigned short AbL2[32][40];
    __shared__ float betL[32];
    const int t = threadIdx.x;
    const int wave = t >> 6, lane = t & 63;
    const int lr = lane & 15, lg = lane >> 4;
    const int l0 = ci * CH;
    const size_t rowbase = (size_t)b * LL + l0;

    // ---- phase 1: stage k,q (bf16, padded rows) + v (f32, padded) + beta
    for (int i = t; i < 1024; i += 256) {
        int r = i >> 5, s8 = (i & 31) * 8;
        *(uint4*)&kL[r][s8] = *(const uint4*)(k + (rowbase + r) * DD + h * DH + s8);
        *(uint4*)&qL[r][s8] = *(const uint4*)(q + (rowbase + r) * DD + h * DH + s8);
    }
    for (int i = t; i < 2048; i += 256) {
        int e = i >> 6, d4 = (i & 63) * 4;
        *(float4*)&vL[e][d4] = *(const float4*)(v + (rowbase + e) * DD + h * DH + d4);
    }
    if (t < 32) betL[t] = beta[(rowbase + t) * HH + h];
    __syncthreads();

    // ---- phase 2: per-wave 16x16 tile of Am (k k^T) and attn (q k^T), K=256
    const int mt = wave >> 1, nt = wave & 1;
    floatx4 accA = (floatx4){0.f,0.f,0.f,0.f}, accT = accA;
#pragma unroll
    for (int ks = 0; ks < 8; ++ks) {
        short8 bk = *(const short8*)&kL[nt * 16 + lr][ks * 32 + lg * 8];
        short8 ak = *(const short8*)&kL[mt * 16 + lr][ks * 32 + lg * 8];
        short8 aq = *(const short8*)&qL[mt * 16 + lr][ks * 32 + lg * 8];
        accA = __builtin_amdgcn_mfma_f32_16x16x32_bf16(ak, bk, accA, 0, 0, 0);
        accT = __builtin_amdgcn_mfma_f32_16x16x32_bf16(aq, bk, accT, 0, 0, 0);
    }
    {
        const size_t abase = (size_t)blockIdx.x * (CH * CH);
        const int ee = nt * 16 + lr;
#pragma unroll
        for (int r = 0; r < 4; ++r) {
            int c = mt * 16 + lg * 4 + r;
            float bc = betL[c];
            AmL[c][ee] = (ee < c) ? (-bc * accA[r]) : 0.0f;
            attn_out[abase + (size_t)c * CH + ee] =
                (ee <= c) ? f2bf(accT[r]) : (unsigned short)0;
        }
    }
    __syncthreads();

    // ---- phase 3: wave 0 substitution; waves 1-3 copy qt + kTt tiles (dense stores)
    unsigned short* qtc  = qt  + (size_t)blockIdx.x * 8192;
    unsigned short* kTtc = kTt + (size_t)blockIdx.x * 8192;
    if (wave == 0) {
        const int j = lane & 31;
        float col[32];
#pragma unroll
        for (int c = 0; c < 32; ++c) col[c] = AmL[c][j];
#pragma unroll
        for (int i = 1; i < 32; ++i) {
            float u0 = 0.f, u1 = 0.f;
#pragma unroll
            for (int kk = 0; kk < 32; kk += 2) {
                if (kk < i)     u0 += __shfl(col[i], kk) * col[kk];
                if (kk + 1 < i) u1 += __shfl(col[i], kk + 1) * col[kk + 1];
            }
            if (j < i) col[i] += u0 + u1;
        }
        if (lane < 32) {
            const float bj = betL[j];
#pragma unroll
            for (int c = 0; c < 32; ++c) {
                float val = (col[c] + (c == j ? 1.0f : 0.0f)) * bj;
                unsigned short hi = f2bf(val);
                AbH[c][j] = hi;
                AbL2[c][j] = f2bf(val - bf2f(hi));
            }
        }
    } else {
        for (int o = t - 64; o < 2048; o += 192) {
            if (o < 1024) {
                int lg2 = o & 3, lr2 = (o >> 2) & 15, kt2 = (o >> 6) & 7, hf = o >> 9;
                short8 val = *(const short8*)&qL[hf * 16 + lr2][kt2 * 32 + lg2 * 8];
                *(short8*)(qtc + (size_t)o * 8) = val;
            } else {
                int o2 = o - 1024;
                int lg2 = o2 & 3, lr2 = (o2 >> 2) & 15, mt2 = (o2 >> 6) & 3, wv = o2 >> 8;
                int e = wv * 64 + mt2 * 16 + lr2;
                union { short8 s8; unsigned short u[8]; } val;
#pragma unroll
                for (int j2 = 0; j2 < 8; ++j2) val.u[j2] = kL[lg2 * 8 + j2][e];
                *(short8*)(kTtc + (size_t)o2 * 8) = val.s8;
            }
        }
    }
    __syncthreads();

    // ---- phase 4: u (tiled, direct to uTt) and w (tiled wt). Dual-bf16 Ab.
    short8 AH[2], ALo[2];
#pragma unroll
    for (int m = 0; m < 2; ++m) {
        AH[m]  = *(const short8*)&AbH[m * 16 + lr][lg * 8];
        ALo[m] = *(const short8*)&AbL2[m * 16 + lr][lg * 8];
    }
    unsigned short* wtc = wt + (size_t)blockIdx.x * 8192;
#pragma unroll
    for (int n = 0; n < 4; ++n) {
        const int d = wave * 64 + n * 16 + lr;
        union { short8 s8; unsigned int u[4]; } vf;
#pragma unroll
        for (int p2 = 0; p2 < 4; ++p2)
            vf.u[p2] = pkbf(vL[lg * 8 + p2 * 2][d], vL[lg * 8 + p2 * 2 + 1][d]);
        union { short8 s8; unsigned short u[8]; } wBv;
#pragma unroll
        for (int j2 = 0; j2 < 8; ++j2) wBv.u[j2] = kL[lg * 8 + j2][d];

        const int jb2 = wave * 4 + n;
        unsigned short* utc = uTt + ((size_t)(bh * 16 + jb2) * NC + ci) * 512;
#pragma unroll
        for (int m = 0; m < 2; ++m) {
            floatx4 au = (floatx4){0.f,0.f,0.f,0.f};
            au = __builtin_amdgcn_mfma_f32_16x16x32_bf16(AH[m],  vf.s8, au, 0, 0, 0);
            au = __builtin_amdgcn_mfma_f32_16x16x32_bf16(ALo[m], vf.s8, au, 0, 0, 0);
            ushort4 ou;
            ou.x = f2bf(au[0]); ou.y = f2bf(au[1]); ou.z = f2bf(au[2]); ou.w = f2bf(au[3]);
            *(ushort4*)(utc + m * 256 + lr * 16 + lg * 4) = ou;

            floatx4 aw = (floatx4){0.f,0.f,0.f,0.f};
            aw = __builtin_amdgcn_mfma_f32_16x16x32_bf16(AH[m],  wBv.s8, aw, 0, 0, 0);
            aw = __builtin_amdgcn_mfma_f32_16x16x32_bf16(ALo[m], wBv.s8, aw, 0, 0, 0);
#pragma unroll
            for (int r = 0; r < 4; ++r) {
                // wt[half=m][kt=d>>5][lr=lg*4+r][lg2=(d>>3)&3][j=d&7]
                int off = m * 4096 + (d >> 5) * 512 + (lg * 4 + r) * 32
                          + ((d >> 3) & 3) * 8 + (d & 7);
                wtc[off] = f2bf(aw[r]);
            }
        }
    }
}

// ------------------------------------------------- chunk scan v13: scan12 skeleton
// (asm-pinned prefetch, counted vmcnt(13|17), 2 LDS-only barriers), dense tiled streams.
__global__ __launch_bounds__(256, 1) void scan13_k(
    const unsigned short* __restrict__ qt, const unsigned short* __restrict__ kTt,
    const unsigned short* __restrict__ uTt, const unsigned short* __restrict__ wt,
    const unsigned short* __restrict__ attn, float* __restrict__ dout)
{
    const int bh = blockIdx.x & 7;     // low bits -> 16 same-bh blocks share one XCD
    const int jb = blockIdx.x >> 3;
    const int jcol = jb * 16;
    const int wave = threadIdx.x >> 6, lane = threadIdx.x & 63;
    const int lr = lane & 15, lg = lane >> 4;
    const int half = wave & 1;
    const bool isQ = wave >= 2;

    __shared__ unsigned short SbT[16][264];    // [col][e] bf16 (single buffer)
    __shared__ unsigned short uadjT[16][40];   // [col][cc] bf16 (single buffer)

    floatx4 Sacc[4];
#pragma unroll
    for (int mtv = 0; mtv < 4; ++mtv) Sacc[mtv] = (floatx4){0.f,0.f,0.f,0.f};

    // dense tiled stream bases (per-lane constant part folded in)
    const unsigned short* potb = (isQ ? qt : wt) + (size_t)bh * NC * 8192
                                 + half * 4096 + lr * 32 + lg * 8;
    const unsigned short* kttb = kTt + (size_t)bh * NC * 8192
                                 + wave * 2048 + lr * 32 + lg * 8;
    const unsigned short* uttb = uTt + (size_t)(bh * 16 + jb) * NC * 512
                                 + half * 256 + lr * 16 + lg * 4;
    const unsigned short* atb  = attn + (size_t)bh * NC * 1024
                                 + (half * 16 + lr) * 32 + lg * 8;
    float* db = dout + (size_t)bh * LL * DH;

    short8 po[2][8];     // this wave's A rows (w or q), K=256
    short8 pk[2][4];     // kT A-frags for S-update
    short8 pa[2];        // attn frag (waves 2,3)
    uint2  pu[2];        // u elems (waves 0,1)

    // 13 pinned loads for chunk cn into register slot s (uniform count all waves)
#define ISSUE13(cn, s)                                                          \
    {                                                                           \
        const size_t co_ = (size_t)(cn) * 8192;                                 \
        po[s][0] = gload16(potb + co_ + 0*512);                                 \
        po[s][1] = gload16(potb + co_ + 1*512);                                 \
        po[s][2] = gload16(potb + co_ + 2*512);                                 \
        po[s][3] = gload16(potb + co_ + 3*512);                                 \
        po[s][4] = gload16(potb + co_ + 4*512);                                 \
        po[s][5] = gload16(potb + co_ + 5*512);                                 \
        po[s][6] = gload16(potb + co_ + 6*512);                                 \
        po[s][7] = gload16(potb + co_ + 7*512);                                 \
        pk[s][0] = gload16(kttb + co_ + 0*512);                                 \
        pk[s][1] = gload16(kttb + co_ + 1*512);                                 \
        pk[s][2] = gload16(kttb + co_ + 2*512);                                 \
        pk[s][3] = gload16(kttb + co_ + 3*512);                                 \
        if (!isQ) pu[s] = gload8(uttb + (size_t)(cn) * 512);                    \
        else      pa[s] = gload16(atb + (size_t)(cn) * 1024);                   \
    }

    // prologue: pin chunk 0's loads -> slot 0
    ISSUE13(0, 0);

#pragma unroll 2
    for (int ci = 0; ci < NC; ++ci) {
        const int p = ci & 1;
        const int l0 = ci * CH;

        // 1) issue pinned loads for chunk ci+1 (clamped tail keeps counts uniform)
        {
            const int cn = (ci + 1 < NC) ? (ci + 1) : ci;
            ISSUE13(cn, p ^ 1);
        }

        // 2) pack wave's S e-slice -> SbT
#pragma unroll
        for (int mtv = 0; mtv < 4; ++mtv) {
            int e0 = 64 * wave + 16 * mtv + lg * 4;
            *(uint2*)&SbT[lr][e0] = make_uint2(pkbf(Sacc[mtv][0], Sacc[mtv][1]),
                                               pkbf(Sacc[mtv][2], Sacc[mtv][3]));
        }
        lds_barrier();   // (a) SbT published; uadjT reads of ci-1 closed

        // 3) counted drain: exactly chunk ci's 13 loads; ci+1's stay in flight.
        if (!isQ || ci == 0) { asm volatile("s_waitcnt vmcnt(13)" ::: "memory"); }
        else                 { asm volatile("s_waitcnt vmcnt(17)" ::: "memory"); }
        __builtin_amdgcn_sched_barrier(0);

        // 4) P = A @ S over full K=256 (two independent chains for ILP)
        floatx4 Pa = (floatx4){0.f,0.f,0.f,0.f}, Pb = Pa;
#pragma unroll
        for (int kt = 0; kt < 4; ++kt) {
            short8 s0 = *(const short8*)&SbT[lr][(2*kt)   * 32 + lg * 8];
            short8 s1 = *(const short8*)&SbT[lr][(2*kt+1) * 32 + lg * 8];
            Pa = __builtin_amdgcn_mfma_f32_16x16x32_bf16(po[p][2*kt],   s0, Pa, 0,0,0);
            Pb = __builtin_amdgcn_mfma_f32_16x16x32_bf16(po[p][2*kt+1], s1, Pb, 0,0,0);
        }
        floatx4 P = Pa + Pb;

        // 5) waves 0,1: uadj = u - w@S -> uadjT
        if (!isQ) {
            float ua0 = bflo(pu[p].x) - P[0];
            float ua1 = bfhi(pu[p].x) - P[1];
            float ua2 = bflo(pu[p].y) - P[2];
            float ua3 = bfhi(pu[p].y) - P[3];
            int cc0 = half * 16 + lg * 4;
            *(uint2*)&uadjT[lr][cc0] = make_uint2(pkbf(ua0, ua1), pkbf(ua2, ua3));
        }
        lds_barrier();   // (b) uadjT visible; SbT reads of this chunk closed

        short8 ub = *(const short8*)&uadjT[lr][lg * 8];

        // 6) waves 2,3: O = q@S + attn@uadj -> dout (4 stores/chunk, counted above)
        if (isQ) {
            floatx4 Ot = __builtin_amdgcn_mfma_f32_16x16x32_bf16(pa[p], ub, P, 0,0,0);
#pragma unroll
            for (int r = 0; r < 4; ++r)
                db[(size_t)(l0 + half * 16 + lg * 4 + r) * DH + jcol + lr] = Ot[r];
        }

        // 7) S e-slice += kT @ uadj
#pragma unroll
        for (int mtv = 0; mtv < 4; ++mtv)
            Sacc[mtv] = __builtin_amdgcn_mfma_f32_16x16x32_bf16(pk[p][mtv], ub, Sacc[mtv], 0,0,0);
    }
#undef ISSUE13
}

// ------------------------------------------------- per-head stats
__global__ __launch_bounds__(256) void stats_k(
    const float* __restrict__ ls, const float* __restrict__ llb,
    const float* __restrict__ dox, const float* __restrict__ v,
    float* __restrict__ stats)
{
    int bl = blockIdx.x;
    int b = bl >> 12, l = bl & (LL - 1);
    int wv = threadIdx.x >> 6, ln = threadIdx.x & 63;
    size_t ibase = (size_t)bl * DD + wv * DH;
    size_t dbase = (((size_t)(b * HH + wv)) * LL + l) * DH;
#pragma unroll
    for (int tn = 0; tn < 4; ++tn) {
        const float* p; size_t base;
        if (tn == 0)      { p = ls;  base = ibase; }
        else if (tn == 1) { p = llb; base = ibase; }
        else if (tn == 2) { p = dox; base = dbase; }
        else              { p = v;   base = ibase; }
        float4 x = *(const float4*)(p + base + ln * 4);
        float sm = x.x + x.y + x.z + x.w;
        float sq = x.x*x.x + x.y*x.y + x.z*x.z + x.w*x.w;
        float sa = fabsf(x.x) + fabsf(x.y) + fabsf(x.z) + fabsf(x.w);
#pragma unroll
        for (int off = 32; off > 0; off >>= 1) {
            sm += __shfl_down(sm, off);
            sq += __shfl_down(sq, off);
            sa += __shfl_down(sa, off);
        }
        if (ln == 0) {
            float mean = sm * (1.0f / DH);
            float var = sq * (1.0f / DH) - mean * mean;
            float am = sa * (1.0f / DH);
            float l2 = sqrtf(sq);
            *(float4*)(stats + (size_t)bl * 64 + wv * 16 + tn * 4) =
                make_float4(mean, var, am, l2);
        }
    }
}

// ------------------------------------------------- gate finish v2
__global__ __launch_bounds__(256) void gate_fin2_k(
    const float* __restrict__ hpart, const float* __restrict__ stats,
    const unsigned short* __restrict__ w1s,
    const float* __restrict__ w2, const float* __restrict__ b2,
    const float* __restrict__ ltemp, float* __restrict__ fw)
{
    const int bl = blockIdx.x;
    const int t = threadIdx.x;
    const float temp = log1pf(expf(ltemp[0])) + 1e-4f;
    __shared__ float st[HH][16];
    __shared__ float red[4][16];
    __shared__ float fin[16];
    if (t < 64) st[t >> 4][t & 15] = stats[(size_t)bl * 64 + t];

    const int e0 = t * 4;
    float4 hp4 = *(const float4*)(hpart + (size_t)bl * DD + e0);
    float hp[4] = {hp4.x, hp4.y, hp4.z, hp4.w};
    float w2a[4][4];
#pragma unroll
    for (int j = 0; j < 4; ++j) {
        float4 wv = *(const float4*)(w2 + (size_t)j * 1024 + e0);
        w2a[j][0] = wv.x; w2a[j][1] = wv.y; w2a[j][2] = wv.z; w2a[j][3] = wv.w;
    }
    uint4 wpk[8];
    const uint4* wp = (const uint4*)(w1s + (size_t)e0 * 16);
#pragma unroll
    for (int i = 0; i < 8; ++i) wpk[i] = wp[i];
    __syncthreads();

    float lg[4][4];
#pragma unroll
    for (int h = 0; h < 4; ++h)
#pragma unroll
        for (int j = 0; j < 4; ++j) lg[h][j] = 0.0f;

#pragma unroll
    for (int ii = 0; ii < 4; ++ii) {
        float xh[4] = {hp[ii], hp[ii], hp[ii], hp[ii]};
        unsigned arr[8] = {wpk[ii*2].x, wpk[ii*2].y, wpk[ii*2].z, wpk[ii*2].w,
                           wpk[ii*2+1].x, wpk[ii*2+1].y, wpk[ii*2+1].z, wpk[ii*2+1].w};
#pragma unroll
        for (int p = 0; p < 8; ++p) {
            float wlo = bflo(arr[p]), whi = bfhi(arr[p]);
            int s = p * 2;
#pragma unroll
            for (int h = 0; h < 4; ++h)
                xh[h] += st[h][s] * wlo + st[h][s + 1] * whi;
        }
#pragma unroll
        for (int h = 0; h < 4; ++h) {
            float x = xh[h];
            float gct = 0.5f * x * (1.0f + erff(x * 0.70710678118654752f));
            lg[h][0] += gct * w2a[0][ii];
            lg[h][1] += gct * w2a[1][ii];
            lg[h][2] += gct * w2a[2][ii];
            lg[h][3] += gct * w2a[3][ii];
        }
    }

#pragma unroll
    for (int h = 0; h < 4; ++h)
#pragma unroll
        for (int j = 0; j < 4; ++j)
#pragma unroll
            for (int off = 32; off > 0; off >>= 1)
                lg[h][j] += __shfl_down(lg[h][j], off);

    const int wv = t >> 6, ln = t & 63;
    if (ln == 0) {
#pragma unroll
        for (int h = 0; h < 4; ++h)
#pragma unroll
            for (int j = 0; j < 4; ++j) red[wv][h * 4 + j] = lg[h][j];
    }
    __syncthreads();
    if (t < 16) {
        float s = red[0][t] + red[1][t] + red[2][t] + red[3][t] + b2[t & 3];
        fin[t] = s / temp;
    }
    __syncthreads();
    if (t < 4) {
        float l0 = fin[t*4], l1 = fin[t*4+1], l2 = fin[t*4+2], l3 = fin[t*4+3];
        float m = fmaxf(fmaxf(l0, l1), fmaxf(l2, l3));
        float e0x = expf(l0-m), e1 = expf(l1-m), e2 = expf(l2-m), e3 = expf(l3-m);
        float inv = 1.0f / (e0x + e1 + e2 + e3);
        *(float4*)(fw + (size_t)bl * 16 + t * 4) = make_float4(e0x*inv, e1*inv, e2*inv, e3*inv);
    }
}

// ------------------------------------------------- combine + rms norm
__global__ __launch_bounds__(256) void combine_k(
    const float* __restrict__ ls, const float* __restrict__ llb,
    const float* __restrict__ dox, const float* __restrict__ v,
    const float* __restrict__ fw, const float* __restrict__ rss,
    const float* __restrict__ rsl, const float* __restrict__ onw,
    float* __restrict__ opre)
{
    int h = blockIdx.x & (HH - 1);
    int bl = blockIdx.x >> 2;
    int b = bl >> 12, l = bl & (LL - 1);
    int d = threadIdx.x;
    size_t i1 = (size_t)blockIdx.x * DH + d;
    size_t i2 = (((size_t)(b * HH + h)) * LL + l) * DH + d;
    const float* fwp = fw + (size_t)blockIdx.x * 4;
    float f0 = fwp[0], f1 = fwp[1], f2 = fwp[2], f3 = fwp[3];
    float aS = rss[0], aL = rsl[0];
    float vls = ls[i1], vll = llb[i1], vd = dox[i2], vv = v[i1];
    float o = f0*vls + f1*vll + f2*vd + f3*vv + aS*vls + aL*vll;
    float s = o * o;
#pragma unroll
    for (int off = 32; off > 0; off >>= 1) s += __shfl_down(s, off);
    __shared__ float red[4];
    int wv = threadIdx.x >> 6, ln = threadIdx.x & 63;
    if (ln == 0) red[wv] = s;
    __syncthreads();
    float ms = (red[0] + red[1] + red[2] + red[3]) * (1.0f / DH);
    opre[(size_t)bl * DD + h * DH + d] = o * rsqrtf(ms + 1e-5f) * onw[d];
}

// ================================================================ launch
extern "C" void kernel_launch(void* const* d_in, const int* in_sizes, int n_in,
                              void* d_out, int out_size, void* d_ws, size_t ws_size,
                              hipStream_t stream)
{
    const float* hs  = (const float*)d_in[0];
    const float* qw  = (const float*)d_in[1];
    const float* kw  = (const float*)d_in[2];
    const float* vw  = (const float*)d_in[3];
    const float* bw  = (const float*)d_in[4];
    const float* qcw = (const float*)d_in[5];
    const float* kcw = (const float*)d_in[6];
    const float* vcw = (const float*)d_in[7];
    const float* fsw = (const float*)d_in[8];
    const float* flw = (const float*)d_in[9];
    const float* w1  = (const float*)d_in[10];
    const float* b1  = (const float*)d_in[11];
    const float* w2  = (const float*)d_in[12];
    const float* b2  = (const float*)d_in[13];
    const float* lt  = (const float*)d_in[14];
    const float* rss = (const float*)d_in[15];
    const float* rsl = (const float*)d_in[16];
    const float* onw = (const float*)d_in[17];
    const float* opw = (const float*)d_in[18];
    float* out = (float*)d_out;

    float* wsf = (float*)d_ws;
    float* tmp   = wsf;
    // tiled scan operand streams (written by chunk_prep3 AFTER the projection phase,
    // so tmp doubles as the bf16 projection scratch during phase 1):
    unsigned short* tmpb = (unsigned short*)tmp;                  // bf16 proj scratch 16MB
    unsigned short* kTtb = (unsigned short*)tmp;                  // 16MB (8*128*16KB)
    unsigned short* uTtb = (unsigned short*)(wsf + BLD/2);        // 16MB (8*16*128*1KB)
    float* vbuf  = wsf + BLD;
    float* dbuf  = wsf + 2*BLD;
    // hsb shares the dbuf region -> DEAD once scan13 writes dbuf. Only used in phase 1.
    unsigned short* hsb = (unsigned short*)(wsf + 2*BLD);
    // bf16 QKV weights live in the dead second half of the dbuf region during phase 1
    unsigned short* qwb = (unsigned short*)(wsf + 2*BLD + BLD/2);
    unsigned short* kwb = qwb + (size_t)DD*DD;
    unsigned short* vwb = kwb + (size_t)DD*DD;
    unsigned short* qbuf = (unsigned short*)(wsf + 3*BLD);
    unsigned short* kbuf = qbuf + BLD;
    float* hpart = wsf + 3*BLD;
    float* opre  = wsf + 3*BLD;
    unsigned short* qtb = (unsigned short*)(wsf + 4*BLD);         // 16MB tiled q
    unsigned short* wtb = qtb + BLD;                              // 16MB tiled w
    float* llbuf = wsf + 4*BLD;   // overlaps qtb/wtb: written only after scan consumed them
    float* lsbuf = tmp;           // overlaps kTtb/uTtb: written only after scan
    unsigned short* attnb = (unsigned short*)(wsf + 5*BLD);
    float* statsb = wsf + 5*BLD + 524288;
    float* fwbuf  = statsb + (size_t)BL*HH*16;
    float* betab  = fwbuf + (size_t)BL*HH*4;
    unsigned short* w1sp = (unsigned short*)(betab + (size_t)BL*HH);

    dim3 gg(8, 64);   // N/128, M/128

    cvt_bf_k<<<(int)(BLD/1024), 256, 0, stream>>>(hs, hsb);
    cvt_bf_k<<<1024, 256, 0, stream>>>(qw, qwb);
    cvt_bf_k<<<1024, 256, 0, stream>>>(kw, kwb);
    cvt_bf_k<<<1024, 256, 0, stream>>>(vw, vwb);
    w1s_prep_k<<<64, 256, 0, stream>>>(w1, w1sp);

    // projections: bf16 output scratch (tmpb at wsf), dead before chunk_prep3
    // writes kTtb/uTtb there. convs read bf16 scratch, write distinct buffers.
    gemm_bb16<<<gg, 256, 0, stream>>>(hsb, DD, qwb, DD, tmpb, DD, DD);
    convnorm_qk_k<<<BL*HH, 256, 0, stream>>>(tmpb, qcw, qbuf);
    gemm_bb16<<<gg, 256, 0, stream>>>(hsb, DD, kwb, DD, tmpb, DD, DD);
    convnorm_qk_k<<<BL*HH, 256, 0, stream>>>(tmpb, kcw, kbuf);
    gemm_bb16<<<gg, 256, 0, stream>>>(hsb, DD, vwb, DD, tmpb, DD, DD);
    conv_silu_k<<<(int)(BLD/256), 256, 0, stream>>>(tmpb, vcw, vbuf);

    beta_k<<<BL, 256, 0, stream>>>(hs, bw, betab);

    // chunk_prep3 emits tiled qt/kTt/wt/uTt + attn
    chunk_prep3_k<<<BB*HH*NC, 256, 0, stream>>>(qbuf, kbuf, vbuf, betab,
                                                qtb, kTtb, wtb, uTtb, attnb);

    scan13_k<<<BB*HH*16, 256, 0, stream>>>(qtb, kTtb, uTtb, wtb, attnb, dbuf);

    fir3_k<5><<<BB*64*16, 256, 0, stream>>>(vbuf, fsw, lsbuf);
    fir3_k<64><<<BB*64*16, 256, 0, stream>>>(vbuf, flw, llbuf);

    stats_k<<<BL, 256, 0, stream>>>(lsbuf, llbuf, dbuf, vbuf, statsb);

    // hpart GEMM reads the pristine f32 input hs (hsb is dead: overwritten by dbuf)
    gemm_mfma<<<gg, 256, 0, stream>>>(hs, DD, w1, 1040, b1, hpart, DD, DD);
    gate_fin2_k<<<BL, 256, 0, stream>>>(hpart, statsb, w1sp, w2, b2, lt, fwbuf);

    combine_k<<<BL*HH, 256, 0, stream>>>(lsbuf, llbuf, dbuf, vbuf, fwbuf, rss, rsl, onw, opre);

    gemm_mfma<<<gg, 256, 0, stream>>>(opre, DD, opw, DD, nullptr, out, DD, DD);
}